// Round 1
// baseline (1450.045 us; speedup 1.0000x reference)
//
#include <hip/hip_runtime.h>
#include <math.h>

#define N_PTS 2048
#define B_SZ  4
#define P_TOT 8192            // B*N
#define JDIM  24576           // P_TOT*3  (GEMM column dim, row stride)
#define K_NN  20

// ---------------------------------------------------------------------------
// KNN: one thread per query point. Batch's points staged in LDS as
// (x,y,z,|p|^2). Top-20 by neg_dist kept as a sorted (ascending) register
// array; strict '>' insertion reproduces jax.lax.top_k earliest-index
// tie-breaking. Self-distance is exactly 0 (max) so self is always included.
// Output: m_out[pt*3+v] = mean of the 20 NN positions.
// ---------------------------------------------------------------------------
__global__ __launch_bounds__(256) void knn_kernel(const float* __restrict__ pts,
                                                  float* __restrict__ m_out)
{
    __shared__ float4 sp[N_PTS];                      // 32 KB
    const int b = blockIdx.x >> 3;                    // 8 blocks per batch
    const int n = ((blockIdx.x & 7) << 8) | threadIdx.x;
    const float* pb = pts + (size_t)b * N_PTS * 3;
    for (int i = threadIdx.x; i < N_PTS; i += 256) {
        float x = pb[i*3+0], y = pb[i*3+1], z = pb[i*3+2];
        sp[i] = make_float4(x, y, z, x*x + y*y + z*z);
    }
    __syncthreads();

    const float4 q = sp[n];
    float t_nd[K_NN];
    int   t_ix[K_NN];
#pragma unroll
    for (int s = 0; s < K_NN; ++s) { t_nd[s] = -INFINITY; t_ix[s] = 0; }

    for (int mi = 0; mi < N_PTS; ++mi) {
        float4 cpt = sp[mi];                          // broadcast read (free)
        float dot = q.x*cpt.x + q.y*cpt.y + q.z*cpt.z;
        float nd  = 2.0f*dot - q.w - cpt.w;           // neg squared distance
        if (nd > t_nd[0]) {                           // strict: earlier idx wins ties
            float cv = nd; int ci = mi;
#pragma unroll
            for (int s = 0; s < K_NN; ++s) {
                float nxt = (s < K_NN-1) ? t_nd[s+1] : INFINITY;
                int   nxi = (s < K_NN-1) ? t_ix[s+1] : 0;
                bool adv = cv > nxt;
                float w_nd = adv ? nxt : cv;
                int   w_ix = adv ? nxi : ci;
                float n_cv = adv ? cv : nxt;
                int   n_ci = adv ? ci : nxi;
                t_nd[s] = w_nd; t_ix[s] = w_ix;
                cv = n_cv; ci = n_ci;
            }
        }
    }

    float sx = 0.f, sy = 0.f, sz = 0.f;
#pragma unroll
    for (int s = 0; s < K_NN; ++s) {
        float4 cpt = sp[t_ix[s]];
        sx += cpt.x; sy += cpt.y; sz += cpt.z;
    }
    const float inv = 1.0f / (float)K_NN;
    const int pt = b * N_PTS + n;
    m_out[pt*3+0] = sx * inv;
    m_out[pt*3+1] = sy * inv;
    m_out[pt*3+2] = sz * inv;
}

// ---------------------------------------------------------------------------
// fc_pos folded with mean-over-k:
//   X[c, pt, v] = W[c,0]*(m-p)[v] + W[c,1]*p[v] + W[c,2]*(m x p)[v]
// X layout: [256, P_TOT, 3] row-major (row stride JDIM).
// ---------------------------------------------------------------------------
__global__ __launch_bounds__(256) void fcpos_kernel(const float* __restrict__ pts,
                                                    const float* __restrict__ m_buf,
                                                    const float* __restrict__ W,
                                                    float* __restrict__ X)
{
    int t  = blockIdx.x * 256 + threadIdx.x;   // [0, 256*8192)
    int c  = t >> 13;                          // channel (wave-uniform)
    int pt = t & 8191;
    float px = pts[pt*3+0], py = pts[pt*3+1], pz = pts[pt*3+2];
    float mx = m_buf[pt*3+0], my = m_buf[pt*3+1], mz = m_buf[pt*3+2];
    float w0 = W[c*3+0], w1 = W[c*3+1], w2 = W[c*3+2];
    float cx = my*pz - mz*py;                  // m x p
    float cy = mz*px - mx*pz;
    float cz = mx*py - my*px;
    float* o = X + (size_t)c * JDIM + pt*3;
    o[0] = w0*(mx-px) + w1*px + w2*cx;
    o[1] = w0*(my-py) + w1*py + w2*cy;
    o[2] = w0*(mz-pz) + w1*pz + w2*cz;
}

// ---------------------------------------------------------------------------
// fp32 GEMM: C[O, JDIM] (+)= W[O, I] @ X[I, JDIM]. 64x64 tile, 256 threads,
// 4x4 micro-tile per thread, K-tile 16. ds_read_b128 for both fragments.
// ---------------------------------------------------------------------------
__global__ __launch_bounds__(256) void gemm_kernel(const float* __restrict__ W,
                                                   const float* __restrict__ X,
                                                   float* __restrict__ C,
                                                   int O, int I, int accum)
{
    __shared__ float Ws[16][64];   // W^T tile: Ws[k][o]
    __shared__ float Xs[16][64];   // Xs[k][j]
    const int tid = threadIdx.x;
    const int jb = blockIdx.x * 64;
    const int ob = blockIdx.y * 64;
    const int tx = tid & 15;
    const int ty = tid >> 4;
    const int wr = tid >> 2;          // 0..63: W row within tile
    const int wk = (tid & 3) << 2;    // 0,4,8,12: k offset
    const int xk = tid >> 4;          // 0..15: X row (k)
    const int xj = (tid & 15) << 2;   // 0..60: j offset

    float acc[4][4];
#pragma unroll
    for (int r = 0; r < 4; ++r)
#pragma unroll
        for (int cc = 0; cc < 4; ++cc) acc[r][cc] = 0.f;

    for (int k0 = 0; k0 < I; k0 += 16) {
        float4 wv = *(const float4*)(W + (size_t)(ob + wr) * I + k0 + wk);
        float4 xv = *(const float4*)(X + (size_t)(k0 + xk) * JDIM + jb + xj);
        Ws[wk+0][wr] = wv.x;
        Ws[wk+1][wr] = wv.y;
        Ws[wk+2][wr] = wv.z;
        Ws[wk+3][wr] = wv.w;
        *(float4*)(&Xs[xk][xj]) = xv;
        __syncthreads();
#pragma unroll
        for (int k = 0; k < 16; ++k) {
            float4 a  = *(const float4*)(&Ws[k][ty << 2]);
            float4 bq = *(const float4*)(&Xs[k][tx << 2]);
            float av[4] = {a.x, a.y, a.z, a.w};
            float bv[4] = {bq.x, bq.y, bq.z, bq.w};
#pragma unroll
            for (int r = 0; r < 4; ++r)
#pragma unroll
                for (int cc = 0; cc < 4; ++cc)
                    acc[r][cc] = fmaf(av[r], bv[cc], acc[r][cc]);
        }
        __syncthreads();
    }

#pragma unroll
    for (int r = 0; r < 4; ++r) {
        float* cp = C + (size_t)(ob + (ty << 2) + r) * JDIM + jb + (tx << 2);
        float4 v = make_float4(acc[r][0], acc[r][1], acc[r][2], acc[r][3]);
        if (accum) {
            float4 prev = *(const float4*)cp;
            v.x += prev.x; v.y += prev.y; v.z += prev.z; v.w += prev.w;
        }
        *(float4*)cp = v;
    }
}

// ---------------------------------------------------------------------------
// VN-LeakyReLU(slope=0): per (channel, point). D <- where(dot>=0, X, X - (dot/dsq)*D)
// X, D: [C, P_TOT, 3]; in-place update of D.
// ---------------------------------------------------------------------------
__global__ __launch_bounds__(256) void vnrelu_kernel(const float* __restrict__ X,
                                                     float* __restrict__ D, int total)
{
    int t = blockIdx.x * 256 + threadIdx.x;
    if (t >= total) return;
    const float* xp = X + (size_t)t * 3;
    float* dp = D + (size_t)t * 3;
    float x0 = xp[0], x1 = xp[1], x2 = xp[2];
    float d0 = dp[0], d1 = dp[1], d2 = dp[2];
    float dot = x0*d0 + x1*d1 + x2*d2;
    if (dot >= 0.f) {
        dp[0] = x0; dp[1] = x1; dp[2] = x2;
    } else {
        float dsq = d0*d0 + d1*d1 + d2*d2 + 1e-8f;
        float s = dot / dsq;
        dp[0] = x0 - s*d0; dp[1] = x1 - s*d1; dp[2] = x2 - s*d2;
    }
}

// ---------------------------------------------------------------------------
// Mean over N points per (c, b, v). X rows are [c][b*N*3 + ...].
// nm layout: [(c*B + b)*3 + v].
// ---------------------------------------------------------------------------
__global__ __launch_bounds__(256) void pool_kernel(const float* __restrict__ X,
                                                   float* __restrict__ nm)
{
    const int c = blockIdx.x;
    const int b = blockIdx.y;
    const float* base = X + (size_t)c * JDIM + b * (N_PTS * 3);
    float s0 = 0.f, s1 = 0.f, s2 = 0.f;
    for (int i = threadIdx.x; i < N_PTS; i += 256) {
        s0 += base[i*3+0];
        s1 += base[i*3+1];
        s2 += base[i*3+2];
    }
    __shared__ float red[3][256];
    red[0][threadIdx.x] = s0; red[1][threadIdx.x] = s1; red[2][threadIdx.x] = s2;
    __syncthreads();
    for (int off = 128; off > 0; off >>= 1) {
        if (threadIdx.x < off) {
            red[0][threadIdx.x] += red[0][threadIdx.x + off];
            red[1][threadIdx.x] += red[1][threadIdx.x + off];
            red[2][threadIdx.x] += red[2][threadIdx.x + off];
        }
        __syncthreads();
    }
    if (threadIdx.x == 0) {
        const float inv = 1.0f / (float)N_PTS;
        nm[(c*B_SZ + b)*3 + 0] = red[0][0] * inv;
        nm[(c*B_SZ + b)*3 + 1] = red[1][0] * inv;
        nm[(c*B_SZ + b)*3 + 2] = red[2][0] * inv;
    }
}

// Broadcast pooled mean into rows [128..255] of the block-input buffer.
__global__ __launch_bounds__(256) void fill_kernel(float* __restrict__ dst,
                                                   const float* __restrict__ nm)
{
    int f = blockIdx.x * 256 + threadIdx.x;   // < 128*JDIM
    int c = f / JDIM;
    int r = f - c * JDIM;
    int b = r / 6144;                         // 6144 = N*3
    int v = r % 3;
    dst[f] = nm[(c*B_SZ + b)*3 + v];
}

// ---------------------------------------------------------------------------
// Final: per batch, d = act_d @ nm_b, VN-ReLU, out = fc_c @ y. 4 blocks x 128.
// ---------------------------------------------------------------------------
__global__ __launch_bounds__(128) void final_kernel(const float* __restrict__ nm,
                                                    const float* __restrict__ act_d,
                                                    const float* __restrict__ fc_c,
                                                    float* __restrict__ out)
{
    const int b = blockIdx.x;
    const int c = threadIdx.x;
    __shared__ float xs[128][3];
    __shared__ float ys[128][3];
    xs[c][0] = nm[(c*B_SZ + b)*3 + 0];
    xs[c][1] = nm[(c*B_SZ + b)*3 + 1];
    xs[c][2] = nm[(c*B_SZ + b)*3 + 2];
    __syncthreads();
    float d0 = 0.f, d1 = 0.f, d2 = 0.f;
    for (int i = 0; i < 128; ++i) {
        float w = act_d[c*128 + i];
        d0 = fmaf(w, xs[i][0], d0);
        d1 = fmaf(w, xs[i][1], d1);
        d2 = fmaf(w, xs[i][2], d2);
    }
    float x0 = xs[c][0], x1 = xs[c][1], x2 = xs[c][2];
    float dot = x0*d0 + x1*d1 + x2*d2;
    float y0, y1, y2;
    if (dot >= 0.f) { y0 = x0; y1 = x1; y2 = x2; }
    else {
        float dsq = d0*d0 + d1*d1 + d2*d2 + 1e-8f;
        float s = dot / dsq;
        y0 = x0 - s*d0; y1 = x1 - s*d1; y2 = x2 - s*d2;
    }
    ys[c][0] = y0; ys[c][1] = y1; ys[c][2] = y2;
    __syncthreads();
    float o0 = 0.f, o1 = 0.f, o2 = 0.f;
    for (int i = 0; i < 128; ++i) {
        float w = fc_c[c*128 + i];
        o0 = fmaf(w, ys[i][0], o0);
        o1 = fmaf(w, ys[i][1], o1);
        o2 = fmaf(w, ys[i][2], o2);
    }
    out[b*384 + c*3 + 0] = o0;
    out[b*384 + c*3 + 1] = o1;
    out[b*384 + c*3 + 2] = o2;
}

// ---------------------------------------------------------------------------
extern "C" void kernel_launch(void* const* d_in, const int* in_sizes, int n_in,
                              void* d_out, int out_size, void* d_ws, size_t ws_size,
                              hipStream_t stream)
{
    const float* p      = (const float*)d_in[0];
    const float* fc_pos = (const float*)d_in[1];
    const float* bd0    = (const float*)d_in[2];   // [5,256,256]
    const float* bW0    = (const float*)d_in[3];   // [5,128,256]
    const float* bd1    = (const float*)d_in[4];   // [5,128,128]
    const float* bW1    = (const float*)d_in[5];   // [5,128,128]
    const float* bWs    = (const float*)d_in[6];   // [5,128,256]
    const float* fc_c   = (const float*)d_in[7];   // [128,128]
    const float* act_d  = (const float*)d_in[8];   // [128,128]
    float* out = (float*)d_out;

    // Workspace layout (floats): m(24576) | nm(1536) | Xa | Xb | T1 (256 rows each)
    float* ws    = (float*)d_ws;
    float* m_buf = ws;
    float* nm    = ws + 24576;
    float* Xa    = ws + 26112;
    float* Xb    = Xa + (size_t)256 * JDIM;
    float* T1    = Xb + (size_t)256 * JDIM;

    knn_kernel<<<dim3(32), dim3(256), 0, stream>>>(p, m_buf);
    fcpos_kernel<<<dim3(8192), dim3(256), 0, stream>>>(p, m_buf, fc_pos, Xa);

    float* Xin = Xa;
    float* Xout = Xb;
    for (int blk = 0; blk < 5; ++blk) {
        const float* D0  = bd0 + (size_t)blk * 256 * 256;
        const float* W0  = bW0 + (size_t)blk * 128 * 256;
        const float* D1  = bd1 + (size_t)blk * 128 * 128;
        const float* W1  = bW1 + (size_t)blk * 128 * 128;
        const float* Wsc = bWs + (size_t)blk * 128 * 256;

        if (blk >= 1) {
            // pooled mean of previous output (rows 0..127 of Xin) -> rows 128..255
            pool_kernel<<<dim3(128, 4), dim3(256), 0, stream>>>(Xin, nm);
            fill_kernel<<<dim3(12288), dim3(256), 0, stream>>>(Xin + (size_t)128 * JDIM, nm);
        }
        // d = D0 @ x
        gemm_kernel<<<dim3(384, 4), dim3(256), 0, stream>>>(D0, Xin, T1, 256, 256, 0);
        // y = vnrelu(x, d)  (in place in T1)
        vnrelu_kernel<<<dim3(8192), dim3(256), 0, stream>>>(Xin, T1, 256 * P_TOT);
        // h = W0 @ y  -> Xout rows 128..255 (scratch region, overwritten later by fill)
        gemm_kernel<<<dim3(384, 2), dim3(256), 0, stream>>>(W0, T1, Xout + (size_t)128 * JDIM, 128, 256, 0);
        // t = D1 @ h -> T1 rows 0..127
        gemm_kernel<<<dim3(384, 2), dim3(256), 0, stream>>>(D1, Xout + (size_t)128 * JDIM, T1, 128, 128, 0);
        // y2 = vnrelu(h, t) in place
        vnrelu_kernel<<<dim3(4096), dim3(256), 0, stream>>>(Xout + (size_t)128 * JDIM, T1, 128 * P_TOT);
        // out = Ws @ x
        gemm_kernel<<<dim3(384, 2), dim3(256), 0, stream>>>(Wsc, Xin, Xout, 128, 256, 0);
        // out += W1 @ y2
        gemm_kernel<<<dim3(384, 2), dim3(256), 0, stream>>>(W1, T1, Xout, 128, 128, 1);

        float* tswap = Xin; Xin = Xout; Xout = tswap;
    }

    pool_kernel<<<dim3(128, 4), dim3(256), 0, stream>>>(Xin, nm);
    final_kernel<<<dim3(4), dim3(128), 0, stream>>>(nm, act_d, fc_c, out);

    (void)in_sizes; (void)n_in; (void)out_size; (void)ws_size;
}

// Round 2
// 1115.990 us; speedup vs baseline: 1.2993x; 1.2993x over previous
//
#include <hip/hip_runtime.h>
#include <math.h>

#define N_PTS 2048
#define B_SZ  4
#define P_TOT 8192            // B*N
#define JDIM  24576           // P_TOT*3  (GEMM column dim, row stride)
#define K_NN  20

// nd must be computed bit-identically in phase 1 and phase 2b.
// q2 = (2qx, 2qy, 2qz, |q|^2); c = (cx, cy, cz, |c|^2)
__device__ __forceinline__ float neg_dist(float4 q2, float4 c) {
    return fmaf(q2.x, c.x, fmaf(q2.y, c.y, fmaf(q2.z, c.z, -q2.w))) - c.w;
}

// ---------------------------------------------------------------------------
// KNN: 256 blocks x 256 threads; 32 queries/block, 8 threads (slices) per
// query, each slicing 256 candidates (mi = j*8 + slice -> conflict-free
// 128B-contiguous LDS reads).
// Phase 1: branchless per-slice top-20 VALUES via sorted-insert identity
//          r[s] = min(max(a[s], v), a[s+1])   (no divergence, 40 VALU/cand).
// Phase 2a: tournament over the 8 slice lists extracts the 20th-largest
//          value T exactly (cross-lane shfl max, tie -> smaller slot).
// Phase 2b: rescan slices, sum positions with nd >= T (bit-identical nd).
// Ties at T are measure-zero for random fp32 data; self (nd=0) always in.
// ---------------------------------------------------------------------------
__global__ __launch_bounds__(256) void knn_kernel(const float* __restrict__ pts,
                                                  float* __restrict__ m_out)
{
    __shared__ float4 sp[N_PTS];                      // 32 KB
    const int b     = blockIdx.x >> 6;                // 64 blocks per batch
    const int qbase = (blockIdx.x & 63) << 5;         // 32 queries per block
    const int ql    = threadIdx.x >> 3;               // 0..31 query within block
    const int sl    = threadIdx.x & 7;                // slice 0..7
    const float* pb = pts + (size_t)b * N_PTS * 3;
    for (int i = threadIdx.x; i < N_PTS; i += 256) {
        float x = pb[i*3+0], y = pb[i*3+1], z = pb[i*3+2];
        sp[i] = make_float4(x, y, z, x*x + y*y + z*z);
    }
    __syncthreads();

    const int n = qbase + ql;
    const float4 q = sp[n];
    const float4 q2 = make_float4(2.f*q.x, 2.f*q.y, 2.f*q.z, q.w);

    float t[K_NN];
#pragma unroll
    for (int s = 0; s < K_NN; ++s) t[s] = -INFINITY;

    // Phase 1: branchless top-20 of my slice (ascending in t[0..19])
    for (int j = 0; j < N_PTS/8; ++j) {
        float4 c = sp[j*8 + sl];
        float v = neg_dist(q2, c);
#pragma unroll
        for (int s = 0; s < K_NN; ++s) {
            float nx = (s < K_NN-1) ? t[s+1] : INFINITY;   // original a[s+1]
            t[s] = fminf(fmaxf(t[s], v), nx);
        }
    }

    // Phase 2a: extract 20 maxima across the 8 slices; T = the 20th.
    float head = t[K_NN-1];
    float T = -INFINITY;
#pragma unroll 1
    for (int e = 0; e < K_NN; ++e) {
        float v = head; int w = sl;
#pragma unroll
        for (int off = 1; off < 8; off <<= 1) {
            float vo = __shfl_xor(v, off);
            int   wo = __shfl_xor(w, off);
            bool take = (vo > v) || (vo == v && wo < w);
            v = take ? vo : v;
            w = take ? wo : w;
        }
        T = v;
        if (w == sl) {            // I own the popped max: shift my list up
#pragma unroll
            for (int s = K_NN-1; s > 0; --s) t[s] = t[s-1];
            t[0] = -INFINITY;
            head = t[K_NN-1];
        }
    }

    // Phase 2b: rescan, sum neighbor positions with nd >= T
    float sx = 0.f, sy = 0.f, sz = 0.f;
    for (int j = 0; j < N_PTS/8; ++j) {
        float4 c = sp[j*8 + sl];
        float v = neg_dist(q2, c);
        if (v >= T) { sx += c.x; sy += c.y; sz += c.z; }
    }
#pragma unroll
    for (int off = 1; off < 8; off <<= 1) {
        sx += __shfl_xor(sx, off);
        sy += __shfl_xor(sy, off);
        sz += __shfl_xor(sz, off);
    }
    if (sl == 0) {
        const float inv = 1.0f / (float)K_NN;
        const int pt = b * N_PTS + n;
        m_out[pt*3+0] = sx * inv;
        m_out[pt*3+1] = sy * inv;
        m_out[pt*3+2] = sz * inv;
    }
}

// ---------------------------------------------------------------------------
// fc_pos folded with mean-over-k:
//   X[c, pt, v] = W[c,0]*(m-p)[v] + W[c,1]*p[v] + W[c,2]*(m x p)[v]
// X layout: [256, P_TOT, 3] row-major (row stride JDIM).
// ---------------------------------------------------------------------------
__global__ __launch_bounds__(256) void fcpos_kernel(const float* __restrict__ pts,
                                                    const float* __restrict__ m_buf,
                                                    const float* __restrict__ W,
                                                    float* __restrict__ X)
{
    int t  = blockIdx.x * 256 + threadIdx.x;   // [0, 256*8192)
    int c  = t >> 13;                          // channel (wave-uniform)
    int pt = t & 8191;
    float px = pts[pt*3+0], py = pts[pt*3+1], pz = pts[pt*3+2];
    float mx = m_buf[pt*3+0], my = m_buf[pt*3+1], mz = m_buf[pt*3+2];
    float w0 = W[c*3+0], w1 = W[c*3+1], w2 = W[c*3+2];
    float cx = my*pz - mz*py;                  // m x p
    float cy = mz*px - mx*pz;
    float cz = mx*py - my*px;
    float* o = X + (size_t)c * JDIM + pt*3;
    o[0] = w0*(mx-px) + w1*px + w2*cx;
    o[1] = w0*(my-py) + w1*py + w2*cy;
    o[2] = w0*(mz-pz) + w1*pz + w2*cz;
}

// ---------------------------------------------------------------------------
// fp32 GEMM: C[O, JDIM] (+)= W[O, I] @ X[I, JDIM].
// 128x128 tile, 256 threads, 8x8 micro-tile, K-tile 16.
// Per k-step: 4 ds_read_b128 (~48 cyc) vs 64 FMA (128 cyc) -> FMA-bound.
// ---------------------------------------------------------------------------
__global__ __launch_bounds__(256) void gemm_kernel(const float* __restrict__ W,
                                                   const float* __restrict__ X,
                                                   float* __restrict__ C,
                                                   int O, int I, int accum)
{
    __shared__ float Ws[16][128];   // W^T tile: Ws[k][o]
    __shared__ float Xs[16][128];   // Xs[k][j]
    const int tid = threadIdx.x;
    const int jb = blockIdx.x * 128;
    const int ob = blockIdx.y * 128;
    const int wrow = tid >> 1;            // 0..127
    const int wk   = (tid & 1) * 8;       // 0 or 8
    const int xkr  = tid >> 4;            // 0..15
    const int xjc  = (tid & 15) * 8;      // 0..120
    const int ty = tid >> 4;              // 0..15 -> 8 rows each
    const int tx = tid & 15;              // 0..15 -> 8 cols each

    float acc[8][8];
#pragma unroll
    for (int r = 0; r < 8; ++r)
#pragma unroll
        for (int cc = 0; cc < 8; ++cc) acc[r][cc] = 0.f;

    const float* Wp = W + (size_t)(ob + wrow) * I + wk;
    const float* Xp = X + (size_t)xkr * JDIM + jb + xjc;

    for (int k0 = 0; k0 < I; k0 += 16) {
        float4 w0 = *(const float4*)(Wp + k0);
        float4 w1 = *(const float4*)(Wp + k0 + 4);
        float4 x0 = *(const float4*)(Xp + (size_t)k0 * JDIM);
        float4 x1 = *(const float4*)(Xp + (size_t)k0 * JDIM + 4);
        __syncthreads();                       // prev iter's readers done
        Ws[wk+0][wrow] = w0.x;
        Ws[wk+1][wrow] = w0.y;
        Ws[wk+2][wrow] = w0.z;
        Ws[wk+3][wrow] = w0.w;
        Ws[wk+4][wrow] = w1.x;
        Ws[wk+5][wrow] = w1.y;
        Ws[wk+6][wrow] = w1.z;
        Ws[wk+7][wrow] = w1.w;
        *(float4*)(&Xs[xkr][xjc])     = x0;
        *(float4*)(&Xs[xkr][xjc + 4]) = x1;
        __syncthreads();
#pragma unroll
        for (int k = 0; k < 16; ++k) {
            float4 a0 = *(const float4*)(&Ws[k][ty*8]);
            float4 a1 = *(const float4*)(&Ws[k][ty*8 + 4]);
            float4 b0 = *(const float4*)(&Xs[k][tx*8]);
            float4 b1 = *(const float4*)(&Xs[k][tx*8 + 4]);
            float av[8] = {a0.x,a0.y,a0.z,a0.w, a1.x,a1.y,a1.z,a1.w};
            float bv[8] = {b0.x,b0.y,b0.z,b0.w, b1.x,b1.y,b1.z,b1.w};
#pragma unroll
            for (int r = 0; r < 8; ++r)
#pragma unroll
                for (int cc = 0; cc < 8; ++cc)
                    acc[r][cc] = fmaf(av[r], bv[cc], acc[r][cc]);
        }
    }

#pragma unroll
    for (int r = 0; r < 8; ++r) {
        float* cp = C + (size_t)(ob + ty*8 + r) * JDIM + jb + tx*8;
        float4 v0 = make_float4(acc[r][0], acc[r][1], acc[r][2], acc[r][3]);
        float4 v1 = make_float4(acc[r][4], acc[r][5], acc[r][6], acc[r][7]);
        if (accum) {
            float4 p0 = *(const float4*)cp;
            float4 p1 = *(const float4*)(cp + 4);
            v0.x += p0.x; v0.y += p0.y; v0.z += p0.z; v0.w += p0.w;
            v1.x += p1.x; v1.y += p1.y; v1.z += p1.z; v1.w += p1.w;
        }
        *(float4*)cp       = v0;
        *(float4*)(cp + 4) = v1;
    }
}

// ---------------------------------------------------------------------------
// VN-LeakyReLU(slope=0), 4 points per thread (3x float4 in/out per matrix).
// D <- where(dot>=0, X, X - (dot/dsq)*D), in place in D.
// total4 = (#rows * P_TOT) / 4
// ---------------------------------------------------------------------------
__global__ __launch_bounds__(256) void vnrelu_kernel(const float* __restrict__ X,
                                                     float* __restrict__ D, int total4)
{
    int t = blockIdx.x * 256 + threadIdx.x;
    if (t >= total4) return;
    const float4* xp = (const float4*)X + (size_t)t * 3;
    float4* dp = (float4*)D + (size_t)t * 3;
    float4 xq0 = xp[0], xq1 = xp[1], xq2 = xp[2];
    float4 dq0 = dp[0], dq1 = dp[1], dq2 = dp[2];
    float xv[12] = {xq0.x,xq0.y,xq0.z,xq0.w, xq1.x,xq1.y,xq1.z,xq1.w, xq2.x,xq2.y,xq2.z,xq2.w};
    float dv[12] = {dq0.x,dq0.y,dq0.z,dq0.w, dq1.x,dq1.y,dq1.z,dq1.w, dq2.x,dq2.y,dq2.z,dq2.w};
    float ov[12];
#pragma unroll
    for (int g = 0; g < 4; ++g) {
        float x0 = xv[g*3+0], x1 = xv[g*3+1], x2 = xv[g*3+2];
        float d0 = dv[g*3+0], d1 = dv[g*3+1], d2 = dv[g*3+2];
        float dot = x0*d0 + x1*d1 + x2*d2;
        float dsq = d0*d0 + d1*d1 + d2*d2 + 1e-8f;
        float s = (dot >= 0.f) ? 0.f : (dot / dsq);
        ov[g*3+0] = x0 - s*d0;
        ov[g*3+1] = x1 - s*d1;
        ov[g*3+2] = x2 - s*d2;
    }
    dp[0] = make_float4(ov[0], ov[1], ov[2],  ov[3]);
    dp[1] = make_float4(ov[4], ov[5], ov[6],  ov[7]);
    dp[2] = make_float4(ov[8], ov[9], ov[10], ov[11]);
}

// ---------------------------------------------------------------------------
// Mean over N points per (c, b, v). nm layout: [(c*B + b)*3 + v].
// ---------------------------------------------------------------------------
__global__ __launch_bounds__(256) void pool_kernel(const float* __restrict__ X,
                                                   float* __restrict__ nm)
{
    const int c = blockIdx.x;
    const int b = blockIdx.y;
    const float* base = X + (size_t)c * JDIM + b * (N_PTS * 3);
    float s0 = 0.f, s1 = 0.f, s2 = 0.f;
    for (int i = threadIdx.x; i < N_PTS; i += 256) {
        s0 += base[i*3+0];
        s1 += base[i*3+1];
        s2 += base[i*3+2];
    }
    __shared__ float red[3][256];
    red[0][threadIdx.x] = s0; red[1][threadIdx.x] = s1; red[2][threadIdx.x] = s2;
    __syncthreads();
    for (int off = 128; off > 0; off >>= 1) {
        if (threadIdx.x < off) {
            red[0][threadIdx.x] += red[0][threadIdx.x + off];
            red[1][threadIdx.x] += red[1][threadIdx.x + off];
            red[2][threadIdx.x] += red[2][threadIdx.x + off];
        }
        __syncthreads();
    }
    if (threadIdx.x == 0) {
        const float inv = 1.0f / (float)N_PTS;
        nm[(c*B_SZ + b)*3 + 0] = red[0][0] * inv;
        nm[(c*B_SZ + b)*3 + 1] = red[1][0] * inv;
        nm[(c*B_SZ + b)*3 + 2] = red[2][0] * inv;
    }
}

// Broadcast pooled mean into rows [128..255] of the block-input buffer.
__global__ __launch_bounds__(256) void fill_kernel(float* __restrict__ dst,
                                                   const float* __restrict__ nm)
{
    int f = blockIdx.x * 256 + threadIdx.x;   // < 128*JDIM
    int c = f / JDIM;
    int r = f - c * JDIM;
    int b = r / 6144;                         // 6144 = N*3
    int v = r % 3;
    dst[f] = nm[(c*B_SZ + b)*3 + v];
}

// ---------------------------------------------------------------------------
// Final: per batch, d = act_d @ nm_b, VN-ReLU, out = fc_c @ y. 4 blocks x 128.
// ---------------------------------------------------------------------------
__global__ __launch_bounds__(128) void final_kernel(const float* __restrict__ nm,
                                                    const float* __restrict__ act_d,
                                                    const float* __restrict__ fc_c,
                                                    float* __restrict__ out)
{
    const int b = blockIdx.x;
    const int c = threadIdx.x;
    __shared__ float xs[128][3];
    __shared__ float ys[128][3];
    xs[c][0] = nm[(c*B_SZ + b)*3 + 0];
    xs[c][1] = nm[(c*B_SZ + b)*3 + 1];
    xs[c][2] = nm[(c*B_SZ + b)*3 + 2];
    __syncthreads();
    float d0 = 0.f, d1 = 0.f, d2 = 0.f;
    for (int i = 0; i < 128; ++i) {
        float w = act_d[c*128 + i];
        d0 = fmaf(w, xs[i][0], d0);
        d1 = fmaf(w, xs[i][1], d1);
        d2 = fmaf(w, xs[i][2], d2);
    }
    float x0 = xs[c][0], x1 = xs[c][1], x2 = xs[c][2];
    float dot = x0*d0 + x1*d1 + x2*d2;
    float y0, y1, y2;
    if (dot >= 0.f) { y0 = x0; y1 = x1; y2 = x2; }
    else {
        float dsq = d0*d0 + d1*d1 + d2*d2 + 1e-8f;
        float s = dot / dsq;
        y0 = x0 - s*d0; y1 = x1 - s*d1; y2 = x2 - s*d2;
    }
    ys[c][0] = y0; ys[c][1] = y1; ys[c][2] = y2;
    __syncthreads();
    float o0 = 0.f, o1 = 0.f, o2 = 0.f;
    for (int i = 0; i < 128; ++i) {
        float w = fc_c[c*128 + i];
        o0 = fmaf(w, ys[i][0], o0);
        o1 = fmaf(w, ys[i][1], o1);
        o2 = fmaf(w, ys[i][2], o2);
    }
    out[b*384 + c*3 + 0] = o0;
    out[b*384 + c*3 + 1] = o1;
    out[b*384 + c*3 + 2] = o2;
}

// ---------------------------------------------------------------------------
extern "C" void kernel_launch(void* const* d_in, const int* in_sizes, int n_in,
                              void* d_out, int out_size, void* d_ws, size_t ws_size,
                              hipStream_t stream)
{
    const float* p      = (const float*)d_in[0];
    const float* fc_pos = (const float*)d_in[1];
    const float* bd0    = (const float*)d_in[2];   // [5,256,256]
    const float* bW0    = (const float*)d_in[3];   // [5,128,256]
    const float* bd1    = (const float*)d_in[4];   // [5,128,128]
    const float* bW1    = (const float*)d_in[5];   // [5,128,128]
    const float* bWs    = (const float*)d_in[6];   // [5,128,256]
    const float* fc_c   = (const float*)d_in[7];   // [128,128]
    const float* act_d  = (const float*)d_in[8];   // [128,128]
    float* out = (float*)d_out;

    // Workspace layout (floats): m(24576) | nm(1536) | Xa | Xb | T1 (256 rows each)
    float* ws    = (float*)d_ws;
    float* m_buf = ws;
    float* nm    = ws + 24576;
    float* Xa    = ws + 26112;
    float* Xb    = Xa + (size_t)256 * JDIM;
    float* T1    = Xb + (size_t)256 * JDIM;

    knn_kernel<<<dim3(256), dim3(256), 0, stream>>>(p, m_buf);
    fcpos_kernel<<<dim3(8192), dim3(256), 0, stream>>>(p, m_buf, fc_pos, Xa);

    float* Xin = Xa;
    float* Xout = Xb;
    for (int blk = 0; blk < 5; ++blk) {
        const float* D0  = bd0 + (size_t)blk * 256 * 256;
        const float* W0  = bW0 + (size_t)blk * 128 * 256;
        const float* D1  = bd1 + (size_t)blk * 128 * 128;
        const float* W1  = bW1 + (size_t)blk * 128 * 128;
        const float* Wsc = bWs + (size_t)blk * 128 * 256;

        if (blk >= 1) {
            pool_kernel<<<dim3(128, 4), dim3(256), 0, stream>>>(Xin, nm);
            fill_kernel<<<dim3(12288), dim3(256), 0, stream>>>(Xin + (size_t)128 * JDIM, nm);
        }
        // d = D0 @ x
        gemm_kernel<<<dim3(192, 2), dim3(256), 0, stream>>>(D0, Xin, T1, 256, 256, 0);
        // y = vnrelu(x, d)  (in place in T1)
        vnrelu_kernel<<<dim3(2048), dim3(256), 0, stream>>>(Xin, T1, 256 * P_TOT / 4);
        // h = W0 @ y  -> Xout rows 128..255 (scratch region, overwritten later by fill)
        gemm_kernel<<<dim3(192, 1), dim3(256), 0, stream>>>(W0, T1, Xout + (size_t)128 * JDIM, 128, 256, 0);
        // t = D1 @ h -> T1 rows 0..127
        gemm_kernel<<<dim3(192, 1), dim3(256), 0, stream>>>(D1, Xout + (size_t)128 * JDIM, T1, 128, 128, 0);
        // y2 = vnrelu(h, t) in place
        vnrelu_kernel<<<dim3(1024), dim3(256), 0, stream>>>(Xout + (size_t)128 * JDIM, T1, 128 * P_TOT / 4);
        // out = Ws @ x
        gemm_kernel<<<dim3(192, 1), dim3(256), 0, stream>>>(Wsc, Xin, Xout, 128, 256, 0);
        // out += W1 @ y2
        gemm_kernel<<<dim3(192, 1), dim3(256), 0, stream>>>(W1, T1, Xout, 128, 128, 1);

        float* tswap = Xin; Xin = Xout; Xout = tswap;
    }

    pool_kernel<<<dim3(128, 4), dim3(256), 0, stream>>>(Xin, nm);
    final_kernel<<<dim3(4), dim3(128), 0, stream>>>(nm, act_d, fc_c, out);

    (void)in_sizes; (void)n_in; (void)out_size; (void)ws_size;
}

// Round 3
// 719.435 us; speedup vs baseline: 2.0155x; 1.5512x over previous
//
#include <hip/hip_runtime.h>
#include <math.h>

#define N_PTS 2048
#define B_SZ  4
#define P_TOT 8192
#define JD    24576           // P_TOT*3 : activation rows (K-major layout [j][C])
#define K_NN  20
#define WTOT  819200          // total weight elements across the 5 tensors

typedef unsigned short u16;
typedef unsigned int   u32;
using short8  = __attribute__((ext_vector_type(8))) short;
using floatx4 = __attribute__((ext_vector_type(4))) float;

// ---- split-bf16 helpers: x ~= hi + lo, error ~2^-17 |x| ---------------------
__device__ __forceinline__ u16 f2bf(float x) {
    u32 u = __float_as_uint(x);
    u32 r = (u + 0x7FFFu + ((u >> 16) & 1u)) >> 16;   // RNE
    return (u16)r;
}
__device__ __forceinline__ float bf2f(u16 h) {
    return __uint_as_float(((u32)h) << 16);
}
__device__ __forceinline__ void split2(float v, u16& h, u16& l) {
    h = f2bf(v);
    l = f2bf(v - bf2f(h));
}

// ---------------------------------------------------------------------------
// Weight conversion: one flat pass over all 5 block-weight tensors.
// hi plane at Wsp[i], lo plane at Wsp[WTOT + i]  -> uniform plane stride WTOT.
// ---------------------------------------------------------------------------
__global__ __launch_bounds__(256) void convert_w(
    const float* __restrict__ bd0, const float* __restrict__ bW0,
    const float* __restrict__ bd1, const float* __restrict__ bW1,
    const float* __restrict__ bWs, u16* __restrict__ Wsp)
{
    int i = blockIdx.x * 256 + threadIdx.x;
    if (i >= WTOT) return;
    float v;
    if      (i < 327680) v = bd0[i];
    else if (i < 491520) v = bW0[i - 327680];
    else if (i < 573440) v = bd1[i - 491520];
    else if (i < 655360) v = bW1[i - 573440];
    else                 v = bWs[i - 655360];
    u16 h, l; split2(v, h, l);
    Wsp[i] = h; Wsp[WTOT + i] = l;
}

// nd must be bit-identical in phase 1 and phase 2b.
__device__ __forceinline__ float neg_dist(float4 q2, float4 c) {
    return fmaf(q2.x, c.x, fmaf(q2.y, c.y, fmaf(q2.z, c.z, -q2.w))) - c.w;
}

// ---------------------------------------------------------------------------
// KNN: 512 blocks x 256 thr; 16 queries/block, 16 slices/query (128 cands
// each). 2 blocks/CU -> 8 waves/CU for latency hiding (was 4).
// ---------------------------------------------------------------------------
__global__ __launch_bounds__(256) void knn_kernel(const float* __restrict__ pts,
                                                  float* __restrict__ m_out)
{
    __shared__ float4 sp[N_PTS];                      // 32 KB
    const int b     = blockIdx.x >> 7;                // 128 blocks per batch
    const int qbase = (blockIdx.x & 127) << 4;        // 16 queries per block
    const int ql    = threadIdx.x >> 4;               // query within block
    const int sl    = threadIdx.x & 15;               // slice 0..15
    const float* pb = pts + (size_t)b * N_PTS * 3;
    for (int i = threadIdx.x; i < N_PTS; i += 256) {
        float x = pb[i*3+0], y = pb[i*3+1], z = pb[i*3+2];
        sp[i] = make_float4(x, y, z, x*x + y*y + z*z);
    }
    __syncthreads();

    const int n = qbase + ql;
    const float4 q = sp[n];
    const float4 q2 = make_float4(2.f*q.x, 2.f*q.y, 2.f*q.z, q.w);

    float t[K_NN];
#pragma unroll
    for (int s = 0; s < K_NN; ++s) t[s] = -INFINITY;

    // Phase 1: branchless sorted top-20 of my 128 candidates
    for (int j = 0; j < N_PTS/16; ++j) {
        float4 c = sp[j*16 + sl];
        float v = neg_dist(q2, c);
#pragma unroll
        for (int s = 0; s < K_NN; ++s) {
            float nx = (s < K_NN-1) ? t[s+1] : INFINITY;
            t[s] = fminf(fmaxf(t[s], v), nx);
        }
    }

    // Phase 2a: pop 20 maxima across the 16 slices; T = the 20th.
    float head = t[K_NN-1];
    float T = -INFINITY;
#pragma unroll 1
    for (int e = 0; e < K_NN; ++e) {
        float v = head; int w = sl;
#pragma unroll
        for (int off = 1; off < 16; off <<= 1) {
            float vo = __shfl_xor(v, off);
            int   wo = __shfl_xor(w, off);
            bool take = (vo > v) || (vo == v && wo < w);
            v = take ? vo : v;
            w = take ? wo : w;
        }
        T = v;
        if (w == sl) {
#pragma unroll
            for (int s = K_NN-1; s > 0; --s) t[s] = t[s-1];
            t[0] = -INFINITY;
            head = t[K_NN-1];
        }
    }

    // Phase 2b: rescan, sum positions with nd >= T
    float sx = 0.f, sy = 0.f, sz = 0.f;
    for (int j = 0; j < N_PTS/16; ++j) {
        float4 c = sp[j*16 + sl];
        float v = neg_dist(q2, c);
        if (v >= T) { sx += c.x; sy += c.y; sz += c.z; }
    }
#pragma unroll
    for (int off = 1; off < 16; off <<= 1) {
        sx += __shfl_xor(sx, off);
        sy += __shfl_xor(sy, off);
        sz += __shfl_xor(sz, off);
    }
    if (sl == 0) {
        const float inv = 1.0f / (float)K_NN;
        const int pt = b * N_PTS + n;
        m_out[pt*3+0] = sx * inv;
        m_out[pt*3+1] = sy * inv;
        m_out[pt*3+2] = sz * inv;
    }
}

// ---------------------------------------------------------------------------
// fc_pos folded with mean-over-k, writing split-bf16 K-major activations:
// X[plane][j = pt*3+v][c] , width 256.  Block per point, thread per channel.
// ---------------------------------------------------------------------------
__global__ __launch_bounds__(256) void fcpos_kernel(const float* __restrict__ pts,
                                                    const float* __restrict__ m_buf,
                                                    const float* __restrict__ W,
                                                    u16* __restrict__ X)
{
    const int pt = blockIdx.x;
    const int c  = threadIdx.x;
    float px = pts[pt*3+0], py = pts[pt*3+1], pz = pts[pt*3+2];
    float mx = m_buf[pt*3+0], my = m_buf[pt*3+1], mz = m_buf[pt*3+2];
    float w0 = W[c*3+0], w1 = W[c*3+1], w2 = W[c*3+2];
    float cx = my*pz - mz*py;
    float cy = mz*px - mx*pz;
    float cz = mx*py - my*px;
    float o0 = w0*(mx-px) + w1*px + w2*cx;
    float o1 = w0*(my-py) + w1*py + w2*cy;
    float o2 = w0*(mz-pz) + w1*pz + w2*cz;
    const size_t ops = (size_t)JD * 256;
    size_t base = (size_t)(pt*3) * 256 + c;
    u16 h, l;
    split2(o0, h, l); X[base      ] = h; X[ops + base      ] = l;
    split2(o1, h, l); X[base + 256] = h; X[ops + base + 256] = l;
    split2(o2, h, l); X[base + 512] = h; X[ops + base + 512] = l;
}

// ---------------------------------------------------------------------------
// Split-bf16 MFMA GEMM (3-pass: AhBh + AhBl + AlBh), C-tile 128(M) x 96(J).
// A: weights [2][M][K] plane stride WTOT, k-contiguous rows.
// B: activations [2][JD][K] (K-major), plane stride JD*K.
// Dual-K: after K1 chunks switch to (A2,B2,K2) -> fused residual add.
// Epilogue: relu=0: write split planes Out[2][JD][Wout] (transposed store).
//           relu=1: LDS-transpose acc, y=vnrelu(x,d) with x=Xbuf, write y.
// grid = (JD/96 = 256, M/128);  256 threads = 4 waves, each 64x48 quadrant.
// ---------------------------------------------------------------------------
__global__ __launch_bounds__(256) void gemm_mfma(
    const u16* __restrict__ A1, const u16* __restrict__ B1, int K1,
    const u16* __restrict__ A2, const u16* __restrict__ B2, int K2,
    u16* __restrict__ Out, int Wout,
    const u16* __restrict__ Xbuf, int relu)
{
    __shared__ union {
        struct {
            u16 Al[2][128][72];   // [plane][m][k] pad 64->72 (16B-aligned rows)
            u16 Bl[2][96][72];    // [plane][j][k]
        } s;
        float C[96][132];         // relu epilogue transpose (pad 128->132)
    } lds;

    const int tid  = threadIdx.x;
    const int jb   = blockIdx.x * 96;
    const int ob   = blockIdx.y * 128;
    const int lane = tid & 63;
    const int wv   = tid >> 6;
    const int qm   = (wv & 1) * 64;       // m-quadrant offset
    const int qn   = (wv >> 1) * 48;      // j-quadrant offset
    const int l15  = lane & 15;
    const int lq8  = (lane >> 4) * 8;

    floatx4 acc[4][3];
#pragma unroll
    for (int mt = 0; mt < 4; ++mt)
#pragma unroll
        for (int nt = 0; nt < 3; ++nt) acc[mt][nt] = (floatx4){0.f,0.f,0.f,0.f};

    const int Ktot = K1 + K2;
    for (int k0 = 0; k0 < Ktot; k0 += 64) {
        const u16* A; const u16* B; int K, kk;
        if (k0 < K1) { A = A1; B = B1; K = K1; kk = k0; }
        else         { A = A2; B = B2; K = K2; kk = k0 - K1; }
        const size_t bps = (size_t)JD * K;
        __syncthreads();
        // stage A: 128 rows x 64 k x 2 planes = 2048 x 16B chunks
#pragma unroll
        for (int i = 0; i < 8; ++i) {
            int qq = tid + 256 * i;
            int pp = qq >> 10;
            int rem = qq & 1023;
            int r = rem >> 3;
            int kc = (rem & 7) << 3;
            uint4 v = *(const uint4*)(A + (size_t)pp * WTOT + (size_t)(ob + r) * K + kk + kc);
            *(uint4*)&lds.s.Al[pp][r][kc] = v;
        }
        // stage B: 96 rows x 64 k x 2 planes = 1536 x 16B chunks
#pragma unroll
        for (int i = 0; i < 6; ++i) {
            int qq = tid + 256 * i;
            int pp = qq >= 768;
            int idx = pp ? qq - 768 : qq;
            int r = idx >> 3;
            int kc = (idx & 7) << 3;
            uint4 v = *(const uint4*)(B + (size_t)pp * bps + (size_t)(jb + r) * K + kk + kc);
            *(uint4*)&lds.s.Bl[pp][r][kc] = v;
        }
        __syncthreads();
#pragma unroll
        for (int sk = 0; sk < 64; sk += 32) {
            short8 af[4][2], bq[3][2];
#pragma unroll
            for (int mt = 0; mt < 4; ++mt)
#pragma unroll
                for (int pp = 0; pp < 2; ++pp)
                    af[mt][pp] = *(const short8*)&lds.s.Al[pp][qm + mt*16 + l15][sk + lq8];
#pragma unroll
            for (int nt = 0; nt < 3; ++nt)
#pragma unroll
                for (int pp = 0; pp < 2; ++pp)
                    bq[nt][pp] = *(const short8*)&lds.s.Bl[pp][qn + nt*16 + l15][sk + lq8];
#pragma unroll
            for (int mt = 0; mt < 4; ++mt)
#pragma unroll
                for (int nt = 0; nt < 3; ++nt) {
                    acc[mt][nt] = __builtin_amdgcn_mfma_f32_16x16x32_bf16(af[mt][0], bq[nt][0], acc[mt][nt], 0, 0, 0);
                    acc[mt][nt] = __builtin_amdgcn_mfma_f32_16x16x32_bf16(af[mt][0], bq[nt][1], acc[mt][nt], 0, 0, 0);
                    acc[mt][nt] = __builtin_amdgcn_mfma_f32_16x16x32_bf16(af[mt][1], bq[nt][0], acc[mt][nt], 0, 0, 0);
                }
        }
    }

    const size_t ops = (size_t)JD * Wout;
    if (!relu) {
        // C/D layout: col(j) = lane&15, row(m) = (lane>>4)*4 + reg
#pragma unroll
        for (int mt = 0; mt < 4; ++mt)
#pragma unroll
            for (int nt = 0; nt < 3; ++nt) {
                int m0 = ob + qm + mt*16 + (lane >> 4) * 4;
                int j  = jb + qn + nt*16 + l15;
                u16 hh[4], ll[4];
#pragma unroll
                for (int r = 0; r < 4; ++r) split2(acc[mt][nt][r], hh[r], ll[r]);
                uint2 hv, lv;
                hv.x = (u32)hh[0] | ((u32)hh[1] << 16);
                hv.y = (u32)hh[2] | ((u32)hh[3] << 16);
                lv.x = (u32)ll[0] | ((u32)ll[1] << 16);
                lv.y = (u32)ll[2] | ((u32)ll[3] << 16);
                *(uint2*)(Out + (size_t)j * Wout + m0)       = hv;
                *(uint2*)(Out + ops + (size_t)j * Wout + m0) = lv;
            }
    } else {
        __syncthreads();                       // staging LDS -> C reuse
#pragma unroll
        for (int mt = 0; mt < 4; ++mt)
#pragma unroll
            for (int nt = 0; nt < 3; ++nt) {
                int ml = qm + mt*16 + (lane >> 4) * 4;
                int jl = qn + nt*16 + l15;
                *(floatx4*)&lds.C[jl][ml] = acc[mt][nt];
            }
        __syncthreads();
        // 32 points x 128 channels; relu couples the 3 vec rows of a point.
#pragma unroll 1
        for (int i = 0; i < 16; ++i) {
            int pr = tid + 256 * i;           // 0..4095
            int pt = pr >> 7;
            int ch = pr & 127;
            int mg = ob + ch;
            float d0 = lds.C[pt*3+0][ch];
            float d1 = lds.C[pt*3+1][ch];
            float d2 = lds.C[pt*3+2][ch];
            size_t j0 = (size_t)(jb + pt*3) * Wout + mg;
            float x0 = bf2f(Xbuf[j0])            + bf2f(Xbuf[ops + j0]);
            float x1 = bf2f(Xbuf[j0 + Wout])     + bf2f(Xbuf[ops + j0 + Wout]);
            float x2 = bf2f(Xbuf[j0 + 2*Wout])   + bf2f(Xbuf[ops + j0 + 2*Wout]);
            float dot = x0*d0 + x1*d1 + x2*d2;
            float y0, y1, y2;
            if (dot >= 0.f) { y0 = x0; y1 = x1; y2 = x2; }
            else {
                float dsq = d0*d0 + d1*d1 + d2*d2 + 1e-8f;
                float s = dot / dsq;
                y0 = x0 - s*d0; y1 = x1 - s*d1; y2 = x2 - s*d2;
            }
            u16 h, l;
            split2(y0, h, l); Out[j0]          = h; Out[ops + j0]          = l;
            split2(y1, h, l); Out[j0 + Wout]   = h; Out[ops + j0 + Wout]   = l;
            split2(y2, h, l); Out[j0 + 2*Wout] = h; Out[ops + j0 + 2*Wout] = l;
        }
    }
}

// ---------------------------------------------------------------------------
// Mean over points: partial sums over 256-point chunks.
// grid (12 = b*3+v, 8 chunks), 128 threads (channel). Reads cols 0..127.
// ---------------------------------------------------------------------------
__global__ __launch_bounds__(128) void pool_kernel(const u16* __restrict__ X,
                                                   float* __restrict__ nm_part)
{
    const int bv = blockIdx.x;
    const int chunk = blockIdx.y;
    const int c = threadIdx.x;
    const int b = bv / 3, v = bv % 3;
    const size_t ops = (size_t)JD * 256;
    float s = 0.f;
    for (int n = chunk*256; n < chunk*256 + 256; ++n) {
        size_t j = (size_t)((b*2048 + n)*3 + v) * 256 + c;
        s += bf2f(X[j]) + bf2f(X[ops + j]);
    }
    nm_part[(chunk*12 + bv)*128 + c] = s;
}

__global__ __launch_bounds__(256) void reduce_kernel(const float* __restrict__ nm_part,
                                                     float* __restrict__ nm_f,
                                                     u16* __restrict__ nm_h,
                                                     u16* __restrict__ nm_l)
{
    int i = blockIdx.x*256 + threadIdx.x;     // 0..1535 = (b*3+v)*128 + c
    if (i >= 1536) return;
    float s = 0.f;
    for (int ch = 0; ch < 8; ++ch) s += nm_part[ch*1536 + i];
    s *= (1.0f/2048.0f);
    nm_f[i] = s;
    split2(s, nm_h[i], nm_l[i]);
}

// Broadcast pooled mean into cols 128..255 of the width-256 block input.
__global__ __launch_bounds__(256) void fill_kernel(u16* __restrict__ X,
                                                   const u16* __restrict__ nm_h,
                                                   const u16* __restrict__ nm_l)
{
    int t = blockIdx.x*256 + threadIdx.x;     // < 24576*32
    int j = t >> 5;
    int c4 = (t & 31) << 2;
    int b = j / 6144;
    int v = j % 3;                            // 6144 % 3 == 0
    const size_t ops = (size_t)JD * 256;
    int nmi = (b*3+v)*128 + c4;
    uint2 hv = *(const uint2*)(nm_h + nmi);
    uint2 lv = *(const uint2*)(nm_l + nmi);
    *(uint2*)(X + (size_t)j*256 + 128 + c4)       = hv;
    *(uint2*)(X + ops + (size_t)j*256 + 128 + c4) = lv;
}

// ---------------------------------------------------------------------------
// Final head: d = act_d @ nm_b, VN-ReLU, out = fc_c @ y.  fp32 throughout.
// nm_f layout: [(b*3+v)*128 + c].
// ---------------------------------------------------------------------------
__global__ __launch_bounds__(128) void final_kernel(const float* __restrict__ nm_f,
                                                    const float* __restrict__ act_d,
                                                    const float* __restrict__ fc_c,
                                                    float* __restrict__ out)
{
    const int b = blockIdx.x;
    const int c = threadIdx.x;
    __shared__ float xs[128][3];
    __shared__ float ys[128][3];
    xs[c][0] = nm_f[(b*3+0)*128 + c];
    xs[c][1] = nm_f[(b*3+1)*128 + c];
    xs[c][2] = nm_f[(b*3+2)*128 + c];
    __syncthreads();
    float d0 = 0.f, d1 = 0.f, d2 = 0.f;
    for (int i = 0; i < 128; ++i) {
        float w = act_d[c*128 + i];
        d0 = fmaf(w, xs[i][0], d0);
        d1 = fmaf(w, xs[i][1], d1);
        d2 = fmaf(w, xs[i][2], d2);
    }
    float x0 = xs[c][0], x1 = xs[c][1], x2 = xs[c][2];
    float dot = x0*d0 + x1*d1 + x2*d2;
    float y0, y1, y2;
    if (dot >= 0.f) { y0 = x0; y1 = x1; y2 = x2; }
    else {
        float dsq = d0*d0 + d1*d1 + d2*d2 + 1e-8f;
        float s = dot / dsq;
        y0 = x0 - s*d0; y1 = x1 - s*d1; y2 = x2 - s*d2;
    }
    ys[c][0] = y0; ys[c][1] = y1; ys[c][2] = y2;
    __syncthreads();
    float o0 = 0.f, o1 = 0.f, o2 = 0.f;
    for (int i = 0; i < 128; ++i) {
        float w = fc_c[c*128 + i];
        o0 = fmaf(w, ys[i][0], o0);
        o1 = fmaf(w, ys[i][1], o1);
        o2 = fmaf(w, ys[i][2], o2);
    }
    out[b*384 + c*3 + 0] = o0;
    out[b*384 + c*3 + 1] = o1;
    out[b*384 + c*3 + 2] = o2;
}

// ---------------------------------------------------------------------------
extern "C" void kernel_launch(void* const* d_in, const int* in_sizes, int n_in,
                              void* d_out, int out_size, void* d_ws, size_t ws_size,
                              hipStream_t stream)
{
    const float* p      = (const float*)d_in[0];
    const float* fc_pos = (const float*)d_in[1];
    const float* bd0    = (const float*)d_in[2];
    const float* bW0    = (const float*)d_in[3];
    const float* bd1    = (const float*)d_in[4];
    const float* bW1    = (const float*)d_in[5];
    const float* bWs    = (const float*)d_in[6];
    const float* fc_c   = (const float*)d_in[7];
    const float* act_d  = (const float*)d_in[8];
    float* out = (float*)d_out;

    // Workspace layout (all offsets 16B-aligned); total ~91.5 MB
    char* w = (char*)d_ws;
    float* m_buf   = (float*)w;  w += 98304;                 // [8192*3] f32
    float* nm_part = (float*)w;  w += 8*1536*4;              // [8][1536]
    float* nm_f    = (float*)w;  w += 6144;                  // [1536]
    u16*   nm_h    = (u16*)w;    w += 3072;
    u16*   nm_l    = (u16*)w;    w += 3072;
    u16*   Wsp     = (u16*)w;    w += (size_t)2*WTOT*2;      // split weights
    u16*   Xa      = (u16*)w;    w += (size_t)2*JD*256*2;
    u16*   Xb      = (u16*)w;    w += (size_t)2*JD*256*2;
    u16*   T       = (u16*)w;    w += (size_t)2*JD*256*2;    // y (w256) then y2 (w128)
    u16*   H       = (u16*)w;    w += (size_t)2*JD*128*2;

    convert_w<<<dim3((WTOT+255)/256), dim3(256), 0, stream>>>(bd0, bW0, bd1, bW1, bWs, Wsp);
    knn_kernel<<<dim3(512), dim3(256), 0, stream>>>(p, m_buf);
    fcpos_kernel<<<dim3(P_TOT), dim3(256), 0, stream>>>(p, m_buf, fc_pos, Xa);

    u16* Xin = Xa;
    u16* Xout = Xb;
    for (int blk = 0; blk < 5; ++blk) {
        const u16* AD0 = Wsp + blk*65536;            // [256,256]
        const u16* AW0 = Wsp + 327680 + blk*32768;   // [128,256]
        const u16* AD1 = Wsp + 491520 + blk*16384;   // [128,128]
        const u16* AW1 = Wsp + 573440 + blk*16384;   // [128,128]
        const u16* AWs = Wsp + 655360 + blk*32768;   // [128,256]

        if (blk >= 1) {
            pool_kernel<<<dim3(12, 8), dim3(128), 0, stream>>>(Xin, nm_part);
            reduce_kernel<<<dim3(6), dim3(256), 0, stream>>>(nm_part, nm_f, nm_h, nm_l);
            fill_kernel<<<dim3(3072), dim3(256), 0, stream>>>(Xin, nm_h, nm_l);
        }
        // y = vnrelu(x, D0@x) -> T (width 256), relu fused in epilogue
        gemm_mfma<<<dim3(256, 2), dim3(256), 0, stream>>>(
            AD0, Xin, 256, nullptr, nullptr, 0, T, 256, Xin, 1);
        // h = W0 @ y -> H (width 128)
        gemm_mfma<<<dim3(256, 1), dim3(256), 0, stream>>>(
            AW0, T, 256, nullptr, nullptr, 0, H, 128, nullptr, 0);
        // y2 = vnrelu(h, D1@h) -> T reused as width-128 buffer
        gemm_mfma<<<dim3(256, 1), dim3(256), 0, stream>>>(
            AD1, H, 128, nullptr, nullptr, 0, T, 128, H, 1);
        // out = Ws@x + W1@y2 -> Xout cols 0..127 (width 256), dual-K fused
        gemm_mfma<<<dim3(256, 1), dim3(256), 0, stream>>>(
            AWs, Xin, 256, AW1, T, 128, Xout, 256, nullptr, 0);

        u16* tmp = Xin; Xin = Xout; Xout = tmp;
    }

    pool_kernel<<<dim3(12, 8), dim3(128), 0, stream>>>(Xin, nm_part);
    reduce_kernel<<<dim3(6), dim3(256), 0, stream>>>(nm_part, nm_f, nm_h, nm_l);
    final_kernel<<<dim3(4), dim3(128), 0, stream>>>(nm_f, act_d, fc_c, out);

    (void)in_sizes; (void)n_in; (void)out_size; (void)ws_size;
}

// Round 5
// 588.822 us; speedup vs baseline: 2.4626x; 1.2218x over previous
//
#include <hip/hip_runtime.h>
#include <math.h>

#define N_PTS 2048
#define B_SZ  4
#define P_TOT 8192
#define JD    24576           // P_TOT*3 : activation rows (K-major layout [j][C])
#define K_NN  20
#define WTOT  819200          // total weight elements across the 5 tensors

typedef unsigned short u16;
typedef unsigned int   u32;
typedef _Float16 f16;
using half8   = __attribute__((ext_vector_type(8))) _Float16;
using floatx4 = __attribute__((ext_vector_type(4))) float;

// Weights: split fp16.  w ~= hi + lo/1024, |err| ~ 2^-24 |w|.
// lo is scaled by 2^10 so it stays in fp16 normal range (no denorm risk).
__device__ __forceinline__ void split2h(float v, f16& h, f16& l) {
    h = (f16)v;
    l = (f16)((v - (float)h) * 1024.0f);
}

// ---------------------------------------------------------------------------
// Weight conversion: hi plane at Wsp[i], scaled-lo plane at Wsp[WTOT+i].
// ---------------------------------------------------------------------------
__global__ __launch_bounds__(256) void convert_w(
    const float* __restrict__ bd0, const float* __restrict__ bW0,
    const float* __restrict__ bd1, const float* __restrict__ bW1,
    const float* __restrict__ bWs, f16* __restrict__ Wsp)
{
    int i = blockIdx.x * 256 + threadIdx.x;
    if (i >= WTOT) return;
    float v;
    if      (i < 327680) v = bd0[i];
    else if (i < 491520) v = bW0[i - 327680];
    else if (i < 573440) v = bd1[i - 491520];
    else if (i < 655360) v = bW1[i - 573440];
    else                 v = bWs[i - 655360];
    f16 h, l; split2h(v, h, l);
    Wsp[i] = h; Wsp[WTOT + i] = l;
}

// nd must be bit-identical in phase 1 and phase 2b.
__device__ __forceinline__ float neg_dist(float4 q2, float4 c) {
    return fmaf(q2.x, c.x, fmaf(q2.y, c.y, fmaf(q2.z, c.z, -q2.w))) - c.w;
}

// ---------------------------------------------------------------------------
// KNN: 1024 blocks x 256 thr; 8 queries/block, 32 slices/query (64 cands
// each). 32 KB LDS -> up to 5 blocks/CU.
// ---------------------------------------------------------------------------
__global__ __launch_bounds__(256) void knn_kernel(const float* __restrict__ pts,
                                                  float* __restrict__ m_out)
{
    __shared__ float4 sp[N_PTS];                      // 32 KB
    const int b     = blockIdx.x >> 8;                // 256 blocks per batch
    const int qbase = (blockIdx.x & 255) << 3;        // 8 queries per block
    const int ql    = threadIdx.x >> 5;               // query within block
    const int sl    = threadIdx.x & 31;               // slice 0..31
    const float* pb = pts + (size_t)b * N_PTS * 3;
    for (int i = threadIdx.x; i < N_PTS; i += 256) {
        float x = pb[i*3+0], y = pb[i*3+1], z = pb[i*3+2];
        sp[i] = make_float4(x, y, z, x*x + y*y + z*z);
    }
    __syncthreads();

    const int n = qbase + ql;
    const float4 q = sp[n];
    const float4 q2 = make_float4(2.f*q.x, 2.f*q.y, 2.f*q.z, q.w);

    float t[K_NN];
#pragma unroll
    for (int s = 0; s < K_NN; ++s) t[s] = -INFINITY;

    // Phase 1: branchless sorted top-20 of my 64 candidates
    for (int j = 0; j < N_PTS/32; ++j) {
        float4 c = sp[j*32 + sl];
        float v = neg_dist(q2, c);
#pragma unroll
        for (int s = 0; s < K_NN; ++s) {
            float nx = (s < K_NN-1) ? t[s+1] : INFINITY;
            t[s] = fminf(fmaxf(t[s], v), nx);
        }
    }

    // Phase 2a: pop 20 maxima across the 32 slices (xor<=16 stays in-group).
    float head = t[K_NN-1];
    float T = -INFINITY;
#pragma unroll 1
    for (int e = 0; e < K_NN; ++e) {
        float v = head; int w = sl;
#pragma unroll
        for (int off = 1; off < 32; off <<= 1) {
            float vo = __shfl_xor(v, off);
            int   wo = __shfl_xor(w, off);
            bool take = (vo > v) || (vo == v && wo < w);
            v = take ? vo : v;
            w = take ? wo : w;
        }
        T = v;
        if (w == sl) {
#pragma unroll
            for (int s = K_NN-1; s > 0; --s) t[s] = t[s-1];
            t[0] = -INFINITY;
            head = t[K_NN-1];
        }
    }

    // Phase 2b: rescan, sum positions with nd >= T
    float sx = 0.f, sy = 0.f, sz = 0.f;
    for (int j = 0; j < N_PTS/32; ++j) {
        float4 c = sp[j*32 + sl];
        float v = neg_dist(q2, c);
        if (v >= T) { sx += c.x; sy += c.y; sz += c.z; }
    }
#pragma unroll
    for (int off = 1; off < 32; off <<= 1) {
        sx += __shfl_xor(sx, off);
        sy += __shfl_xor(sy, off);
        sz += __shfl_xor(sz, off);
    }
    if (sl == 0) {
        const float inv = 1.0f / (float)K_NN;
        const int pt = b * N_PTS + n;
        m_out[pt*3+0] = sx * inv;
        m_out[pt*3+1] = sy * inv;
        m_out[pt*3+2] = sz * inv;
    }
}

// ---------------------------------------------------------------------------
// fc_pos folded with mean-over-k -> fp16 K-major X[j][c], width 256.
// ---------------------------------------------------------------------------
__global__ __launch_bounds__(256) void fcpos_kernel(const float* __restrict__ pts,
                                                    const float* __restrict__ m_buf,
                                                    const float* __restrict__ W,
                                                    f16* __restrict__ X)
{
    const int pt = blockIdx.x;
    const int c  = threadIdx.x;
    float px = pts[pt*3+0], py = pts[pt*3+1], pz = pts[pt*3+2];
    float mx = m_buf[pt*3+0], my = m_buf[pt*3+1], mz = m_buf[pt*3+2];
    float w0 = W[c*3+0], w1 = W[c*3+1], w2 = W[c*3+2];
    float cx = my*pz - mz*py;
    float cy = mz*px - mx*pz;
    float cz = mx*py - my*px;
    float o0 = w0*(mx-px) + w1*px + w2*cx;
    float o1 = w0*(my-py) + w1*py + w2*cy;
    float o2 = w0*(mz-pz) + w1*pz + w2*cz;
    size_t base = (size_t)(pt*3) * 256 + c;
    X[base      ] = (f16)o0;
    X[base + 256] = (f16)o1;
    X[base + 512] = (f16)o2;
}

// ---------------------------------------------------------------------------
// fp16 MFMA GEMM, 2-pass split weights (hi + lo/1024, dual accumulators).
// C-tile 128(M) x 96(J), 512 threads = 8 waves, each a 32(M) x 48(J) tile.
// A: weights [2][M][K] plane stride WTOT. B: activations [JD][K] fp16.
// Dual-K: after K1 chunks switch to (A2,B2,K2) -> fused residual add.
// Epilogue relu=0: Out[j][m] fp16 (transposed store from C-frag layout).
//          relu=1: LDS-transpose acc, y = vnrelu(x=Xbuf, d), write y.
// grid = (JD/96=256, M/128).
// ---------------------------------------------------------------------------
__global__ __launch_bounds__(512) void gemm_mfma(
    const f16* __restrict__ A1, const f16* __restrict__ B1, int K1,
    const f16* __restrict__ A2, const f16* __restrict__ B2, int K2,
    f16* __restrict__ Out, int Wout,
    const f16* __restrict__ Xbuf, int relu)
{
    __shared__ union {
        struct {
            f16 Al[2][128][72];   // [plane][m][k] pad 64->72 (2-way max, free)
            f16 Bl[96][72];       // [j][k]
        } s;
        float C[96][132];         // relu epilogue transpose (pad 128->132)
    } lds;

    const int tid  = threadIdx.x;
    const int jb   = blockIdx.x * 96;
    const int ob   = blockIdx.y * 128;
    const int lane = tid & 63;
    const int wv   = tid >> 6;            // 0..7
    const int qm   = (wv & 3) * 32;       // m-quadrant offset (4 x 32)
    const int qn   = (wv >> 2) * 48;      // j-quadrant offset (2 x 48)
    const int l15  = lane & 15;
    const int lq8  = (lane >> 4) * 8;

    floatx4 acc[2][3], accL[2][3];
#pragma unroll
    for (int mt = 0; mt < 2; ++mt)
#pragma unroll
        for (int nt = 0; nt < 3; ++nt) {
            acc[mt][nt]  = (floatx4){0.f,0.f,0.f,0.f};
            accL[mt][nt] = (floatx4){0.f,0.f,0.f,0.f};
        }

    const int Ktot = K1 + K2;
    for (int k0 = 0; k0 < Ktot; k0 += 64) {
        const f16* A; const f16* B; int K, kk;
        if (k0 < K1) { A = A1; B = B1; K = K1; kk = k0; }
        else         { A = A2; B = B2; K = K2; kk = k0 - K1; }
        __syncthreads();
        // stage A: 2 planes x 128 rows x 64 k = 2048 x 16B chunks, 4/thread
#pragma unroll
        for (int i = 0; i < 4; ++i) {
            int qq = tid + 512 * i;
            int pp = qq >> 10;
            int rem = qq & 1023;
            int r = rem >> 3;
            int kc = (rem & 7) << 3;
            uint4 v = *(const uint4*)(A + (size_t)pp * WTOT + (size_t)(ob + r) * K + kk + kc);
            *(uint4*)&lds.s.Al[pp][r][kc] = v;
        }
        // stage B: 96 rows x 64 k = 768 x 16B chunks
#pragma unroll
        for (int i = 0; i < 2; ++i) {
            int idx = tid + 512 * i;
            if (idx < 768) {
                int r = idx >> 3;
                int kc = (idx & 7) << 3;
                uint4 v = *(const uint4*)(B + (size_t)(jb + r) * K + kk + kc);
                *(uint4*)&lds.s.Bl[r][kc] = v;
            }
        }
        __syncthreads();
#pragma unroll
        for (int sk = 0; sk < 64; sk += 32) {
            half8 afh[2], afl[2], bq[3];
#pragma unroll
            for (int mt = 0; mt < 2; ++mt) {
                afh[mt] = *(const half8*)&lds.s.Al[0][qm + mt*16 + l15][sk + lq8];
                afl[mt] = *(const half8*)&lds.s.Al[1][qm + mt*16 + l15][sk + lq8];
            }
#pragma unroll
            for (int nt = 0; nt < 3; ++nt)
                bq[nt] = *(const half8*)&lds.s.Bl[qn + nt*16 + l15][sk + lq8];
#pragma unroll
            for (int mt = 0; mt < 2; ++mt)
#pragma unroll
                for (int nt = 0; nt < 3; ++nt) {
                    acc[mt][nt]  = __builtin_amdgcn_mfma_f32_16x16x32_f16(afh[mt], bq[nt], acc[mt][nt], 0, 0, 0);
                    accL[mt][nt] = __builtin_amdgcn_mfma_f32_16x16x32_f16(afl[mt], bq[nt], accL[mt][nt], 0, 0, 0);
                }
        }
    }

    // recombine split-weight passes
    floatx4 res[2][3];
#pragma unroll
    for (int mt = 0; mt < 2; ++mt)
#pragma unroll
        for (int nt = 0; nt < 3; ++nt) {
#pragma unroll
            for (int r = 0; r < 4; ++r)
                res[mt][nt][r] = acc[mt][nt][r] + accL[mt][nt][r] * (1.0f/1024.0f);
        }

    if (!relu) {
        // C/D layout: col(j) = lane&15, row(m) = (lane>>4)*4 + reg
#pragma unroll
        for (int mt = 0; mt < 2; ++mt)
#pragma unroll
            for (int nt = 0; nt < 3; ++nt) {
                int m0 = ob + qm + mt*16 + (lane >> 4) * 4;
                int j  = jb + qn + nt*16 + l15;
                u16 hh[4];
#pragma unroll
                for (int r = 0; r < 4; ++r) {
                    f16 hv = (f16)res[mt][nt][r];
                    hh[r] = *(u16*)&hv;
                }
                uint2 pv;
                pv.x = (u32)hh[0] | ((u32)hh[1] << 16);
                pv.y = (u32)hh[2] | ((u32)hh[3] << 16);
                *(uint2*)(Out + (size_t)j * Wout + m0) = pv;
            }
    } else {
        __syncthreads();                       // staging LDS -> C reuse
#pragma unroll
        for (int mt = 0; mt < 2; ++mt)
#pragma unroll
            for (int nt = 0; nt < 3; ++nt) {
                int ml = qm + mt*16 + (lane >> 4) * 4;
                int jl = qn + nt*16 + l15;
                *(floatx4*)&lds.C[jl][ml] = res[mt][nt];
            }
        __syncthreads();
        // 32 points x 128 channels; relu couples the 3 vec rows of a point.
#pragma unroll 1
        for (int i = 0; i < 8; ++i) {
            int pr = tid + 512 * i;           // 0..4095
            int pt = pr >> 7;
            int ch = pr & 127;
            int mg = ob + ch;
            float d0 = lds.C[pt*3+0][ch];
            float d1 = lds.C[pt*3+1][ch];
            float d2 = lds.C[pt*3+2][ch];
            size_t j0 = (size_t)(jb + pt*3) * Wout + mg;
            float x0 = (float)Xbuf[j0];
            float x1 = (float)Xbuf[j0 + Wout];
            float x2 = (float)Xbuf[j0 + 2*Wout];
            float dot = x0*d0 + x1*d1 + x2*d2;
            float y0, y1, y2;
            if (dot >= 0.f) { y0 = x0; y1 = x1; y2 = x2; }
            else {
                float dsq = d0*d0 + d1*d1 + d2*d2 + 1e-8f;
                float s = dot / dsq;
                y0 = x0 - s*d0; y1 = x1 - s*d1; y2 = x2 - s*d2;
            }
            Out[j0]          = (f16)y0;
            Out[j0 + Wout]   = (f16)y1;
            Out[j0 + 2*Wout] = (f16)y2;
        }
    }
}

// ---------------------------------------------------------------------------
// Mean over points: partial sums over 256-point chunks. Reads cols 0..127.
// ---------------------------------------------------------------------------
__global__ __launch_bounds__(128) void pool_kernel(const f16* __restrict__ X,
                                                   float* __restrict__ nm_part)
{
    const int bv = blockIdx.x;
    const int chunk = blockIdx.y;
    const int c = threadIdx.x;
    const int b = bv / 3, v = bv % 3;
    float s = 0.f;
    for (int n = chunk*256; n < chunk*256 + 256; ++n) {
        size_t j = (size_t)((b*2048 + n)*3 + v) * 256 + c;
        s += (float)X[j];
    }
    nm_part[(chunk*12 + bv)*128 + c] = s;
}

__global__ __launch_bounds__(256) void reduce_kernel(const float* __restrict__ nm_part,
                                                     float* __restrict__ nm_f,
                                                     f16* __restrict__ nm_h)
{
    int i = blockIdx.x*256 + threadIdx.x;     // 0..1535 = (b*3+v)*128 + c
    if (i >= 1536) return;
    float s = 0.f;
    for (int ch = 0; ch < 8; ++ch) s += nm_part[ch*1536 + i];
    s *= (1.0f/2048.0f);
    nm_f[i] = s;
    nm_h[i] = (f16)s;
}

// Broadcast pooled mean into cols 128..255 of the width-256 block input.
__global__ __launch_bounds__(256) void fill_kernel(f16* __restrict__ X,
                                                   const f16* __restrict__ nm_h)
{
    int t = blockIdx.x*256 + threadIdx.x;     // < 24576*32
    int j = t >> 5;
    int c4 = (t & 31) << 2;
    int b = j / 6144;
    int v = j % 3;                            // 6144 % 3 == 0
    int nmi = (b*3+v)*128 + c4;
    uint2 hv = *(const uint2*)(nm_h + nmi);
    *(uint2*)(X + (size_t)j*256 + 128 + c4) = hv;
}

// ---------------------------------------------------------------------------
// Final head: d = act_d @ nm_b, VN-ReLU, out = fc_c @ y. fp32 throughout.
// ---------------------------------------------------------------------------
__global__ __launch_bounds__(128) void final_kernel(const float* __restrict__ nm_f,
                                                    const float* __restrict__ act_d,
                                                    const float* __restrict__ fc_c,
                                                    float* __restrict__ out)
{
    const int b = blockIdx.x;
    const int c = threadIdx.x;
    __shared__ float xs[128][3];
    __shared__ float ys[128][3];
    xs[c][0] = nm_f[(b*3+0)*128 + c];
    xs[c][1] = nm_f[(b*3+1)*128 + c];
    xs[c][2] = nm_f[(b*3+2)*128 + c];
    __syncthreads();
    float d0 = 0.f, d1 = 0.f, d2 = 0.f;
    for (int i = 0; i < 128; ++i) {
        float w = act_d[c*128 + i];
        d0 = fmaf(w, xs[i][0], d0);
        d1 = fmaf(w, xs[i][1], d1);
        d2 = fmaf(w, xs[i][2], d2);
    }
    float x0 = xs[c][0], x1 = xs[c][1], x2 = xs[c][2];
    float dot = x0*d0 + x1*d1 + x2*d2;
    float y0, y1, y2;
    if (dot >= 0.f) { y0 = x0; y1 = x1; y2 = x2; }
    else {
        float dsq = d0*d0 + d1*d1 + d2*d2 + 1e-8f;
        float s = dot / dsq;
        y0 = x0 - s*d0; y1 = x1 - s*d1; y2 = x2 - s*d2;
    }
    ys[c][0] = y0; ys[c][1] = y1; ys[c][2] = y2;
    __syncthreads();
    float o0 = 0.f, o1 = 0.f, o2 = 0.f;
    for (int i = 0; i < 128; ++i) {
        float w = fc_c[c*128 + i];
        o0 = fmaf(w, ys[i][0], o0);
        o1 = fmaf(w, ys[i][1], o1);
        o2 = fmaf(w, ys[i][2], o2);
    }
    out[b*384 + c*3 + 0] = o0;
    out[b*384 + c*3 + 1] = o1;
    out[b*384 + c*3 + 2] = o2;
}

// ---------------------------------------------------------------------------
extern "C" void kernel_launch(void* const* d_in, const int* in_sizes, int n_in,
                              void* d_out, int out_size, void* d_ws, size_t ws_size,
                              hipStream_t stream)
{
    const float* p      = (const float*)d_in[0];
    const float* fc_pos = (const float*)d_in[1];
    const float* bd0    = (const float*)d_in[2];
    const float* bW0    = (const float*)d_in[3];
    const float* bd1    = (const float*)d_in[4];
    const float* bW1    = (const float*)d_in[5];
    const float* bWs    = (const float*)d_in[6];
    const float* fc_c   = (const float*)d_in[7];
    const float* act_d  = (const float*)d_in[8];
    float* out = (float*)d_out;

    // Workspace layout (16B-aligned)
    char* w = (char*)d_ws;
    float* m_buf   = (float*)w;  w += 98304;                 // [8192*3] f32
    float* nm_part = (float*)w;  w += 8*1536*4;              // [8][1536]
    float* nm_f    = (float*)w;  w += 6144;                  // [1536]
    f16*   nm_h    = (f16*)w;    w += 3072 + 1024;           // pad to 16B
    f16*   Wsp     = (f16*)w;    w += (size_t)2*WTOT*2;      // split weights
    f16*   Xa      = (f16*)w;    w += (size_t)JD*256*2;
    f16*   Xb      = (f16*)w;    w += (size_t)JD*256*2;
    f16*   T       = (f16*)w;    w += (size_t)JD*256*2;      // y (w256) then y2 (w128)
    f16*   H       = (f16*)w;    w += (size_t)JD*128*2;

    convert_w<<<dim3((WTOT+255)/256), dim3(256), 0, stream>>>(bd0, bW0, bd1, bW1, bWs, Wsp);
    knn_kernel<<<dim3(1024), dim3(256), 0, stream>>>(p, m_buf);
    fcpos_kernel<<<dim3(P_TOT), dim3(256), 0, stream>>>(p, m_buf, fc_pos, Xa);

    f16* Xin = Xa;
    f16* Xout = Xb;
    for (int blk = 0; blk < 5; ++blk) {
        const f16* AD0 = Wsp + blk*65536;            // [256,256]
        const f16* AW0 = Wsp + 327680 + blk*32768;   // [128,256]
        const f16* AD1 = Wsp + 491520 + blk*16384;   // [128,128]
        const f16* AW1 = Wsp + 573440 + blk*16384;   // [128,128]
        const f16* AWs = Wsp + 655360 + blk*32768;   // [128,256]

        if (blk >= 1) {
            pool_kernel<<<dim3(12, 8), dim3(128), 0, stream>>>(Xin, nm_part);
            reduce_kernel<<<dim3(6), dim3(256), 0, stream>>>(nm_part, nm_f, nm_h);
            fill_kernel<<<dim3(3072), dim3(256), 0, stream>>>(Xin, nm_h);
        }
        // y = vnrelu(x, D0@x) -> T (width 256), relu fused in epilogue
        gemm_mfma<<<dim3(256, 2), dim3(512), 0, stream>>>(
            AD0, Xin, 256, nullptr, nullptr, 0, T, 256, Xin, 1);
        // h = W0 @ y -> H (width 128)
        gemm_mfma<<<dim3(256, 1), dim3(512), 0, stream>>>(
            AW0, T, 256, nullptr, nullptr, 0, H, 128, nullptr, 0);
        // y2 = vnrelu(h, D1@h) -> T reused as width-128 buffer
        gemm_mfma<<<dim3(256, 1), dim3(512), 0, stream>>>(
            AD1, H, 128, nullptr, nullptr, 0, T, 128, H, 1);
        // out = Ws@x + W1@y2 -> Xout cols 0..127 (width 256), dual-K fused
        gemm_mfma<<<dim3(256, 1), dim3(512), 0, stream>>>(
            AWs, Xin, 256, AW1, T, 128, Xout, 256, nullptr, 0);

        f16* tmp = Xin; Xin = Xout; Xout = tmp;
    }

    pool_kernel<<<dim3(12, 8), dim3(128), 0, stream>>>(Xin, nm_part);
    reduce_kernel<<<dim3(6), dim3(256), 0, stream>>>(nm_part, nm_f, nm_h);
    final_kernel<<<dim3(4), dim3(128), 0, stream>>>(nm_f, act_d, fc_c, out);

    (void)in_sizes; (void)n_in; (void)out_size; (void)ws_size;
}

// Round 7
// 573.993 us; speedup vs baseline: 2.5262x; 1.0258x over previous
//
#include <hip/hip_runtime.h>
#include <math.h>

#define N_PTS 2048
#define B_SZ  4
#define P_TOT 8192
#define JD    24576           // P_TOT*3 : activation rows (K-major layout [j][C])
#define K_NN  20
#define WTOT  819200          // total weight elements across the 5 tensors

typedef unsigned short u16;
typedef unsigned int   u32;
typedef _Float16 f16;
using half8   = __attribute__((ext_vector_type(8))) _Float16;
using floatx4 = __attribute__((ext_vector_type(4))) float;

// Weights: split fp16.  w ~= hi + lo/1024, |err| ~ 2^-24 |w|.
__device__ __forceinline__ void split2h(float v, f16& h, f16& l) {
    h = (f16)v;
    l = (f16)((v - (float)h) * 1024.0f);
}

// ---------------------------------------------------------------------------
// Weight conversion + MFMA-fragment swizzle.
// Swizzled layout per matrix region: frag (mf, kf) is 64 lanes x 8 f16
// contiguous (1KB):  element (lane=q*16+r, i) -> A[m=mf*16+r][k=kf*32+q*8+i]
// (verified 16x16x32 A-operand mapping).  hi plane at [dst], lo at [WTOT+dst].
// ---------------------------------------------------------------------------
__global__ __launch_bounds__(256) void convert_w(
    const float* __restrict__ bd0, const float* __restrict__ bW0,
    const float* __restrict__ bd1, const float* __restrict__ bW1,
    const float* __restrict__ bWs, u16* __restrict__ Wswz)
{
    int i = blockIdx.x * 256 + threadIdx.x;
    if (i >= WTOT) return;
    float v; int base, K, local;
    if (i < 327680)      { int rel = i;          base = (rel/65536)*65536;            local = rel%65536; K = 256; v = bd0[rel]; }
    else if (i < 491520) { int rel = i - 327680; base = 327680 + (rel/32768)*32768;   local = rel%32768; K = 256; v = bW0[rel]; }
    else if (i < 573440) { int rel = i - 491520; base = 491520 + (rel/16384)*16384;   local = rel%16384; K = 128; v = bd1[rel]; }
    else if (i < 655360) { int rel = i - 573440; base = 573440 + (rel/16384)*16384;   local = rel%16384; K = 128; v = bW1[rel]; }
    else                 { int rel = i - 655360; base = 655360 + (rel/32768)*32768;   local = rel%32768; K = 256; v = bWs[rel]; }
    int m = local / K, k = local % K;
    int NKF = K >> 5;
    int mf = m >> 4, r = m & 15;
    int kf = k >> 5, q = (k >> 3) & 3, ii = k & 7;
    int lane = q*16 + r;
    int dst = base + ((mf*NKF + kf)*64 + lane)*8 + ii;
    f16 h, l; split2h(v, h, l);
    f16* W = (f16*)Wswz;
    W[dst] = h; W[WTOT + dst] = l;
}

// nd must be bit-identical in phase 1 and phase 2b.
__device__ __forceinline__ float neg_dist(float4 q2, float4 c) {
    return fmaf(q2.x, c.x, fmaf(q2.y, c.y, fmaf(q2.z, c.z, -q2.w))) - c.w;
}

// ---------------------------------------------------------------------------
// KNN: 1024 blocks x 256 thr; 8 queries/block, 32 slices/query.
// ---------------------------------------------------------------------------
__global__ __launch_bounds__(256) void knn_kernel(const float* __restrict__ pts,
                                                  float* __restrict__ m_out)
{
    __shared__ float4 sp[N_PTS];                      // 32 KB
    const int b     = blockIdx.x >> 8;
    const int qbase = (blockIdx.x & 255) << 3;
    const int ql    = threadIdx.x >> 5;
    const int sl    = threadIdx.x & 31;
    const float* pb = pts + (size_t)b * N_PTS * 3;
    for (int i = threadIdx.x; i < N_PTS; i += 256) {
        float x = pb[i*3+0], y = pb[i*3+1], z = pb[i*3+2];
        sp[i] = make_float4(x, y, z, x*x + y*y + z*z);
    }
    __syncthreads();

    const int n = qbase + ql;
    const float4 q = sp[n];
    const float4 q2 = make_float4(2.f*q.x, 2.f*q.y, 2.f*q.z, q.w);

    float t[K_NN];
#pragma unroll
    for (int s = 0; s < K_NN; ++s) t[s] = -INFINITY;

    for (int j = 0; j < N_PTS/32; ++j) {
        float4 c = sp[j*32 + sl];
        float v = neg_dist(q2, c);
#pragma unroll
        for (int s = 0; s < K_NN; ++s) {
            float nx = (s < K_NN-1) ? t[s+1] : INFINITY;
            t[s] = fminf(fmaxf(t[s], v), nx);
        }
    }

    float head = t[K_NN-1];
    float T = -INFINITY;
#pragma unroll 1
    for (int e = 0; e < K_NN; ++e) {
        float v = head; int w = sl;
#pragma unroll
        for (int off = 1; off < 32; off <<= 1) {
            float vo = __shfl_xor(v, off);
            int   wo = __shfl_xor(w, off);
            bool take = (vo > v) || (vo == v && wo < w);
            v = take ? vo : v;
            w = take ? wo : w;
        }
        T = v;
        if (w == sl) {
#pragma unroll
            for (int s = K_NN-1; s > 0; --s) t[s] = t[s-1];
            t[0] = -INFINITY;
            head = t[K_NN-1];
        }
    }

    float sx = 0.f, sy = 0.f, sz = 0.f;
    for (int j = 0; j < N_PTS/32; ++j) {
        float4 c = sp[j*32 + sl];
        float v = neg_dist(q2, c);
        if (v >= T) { sx += c.x; sy += c.y; sz += c.z; }
    }
#pragma unroll
    for (int off = 1; off < 32; off <<= 1) {
        sx += __shfl_xor(sx, off);
        sy += __shfl_xor(sy, off);
        sz += __shfl_xor(sz, off);
    }
    if (sl == 0) {
        const float inv = 1.0f / (float)K_NN;
        const int pt = b * N_PTS + n;
        m_out[pt*3+0] = sx * inv;
        m_out[pt*3+1] = sy * inv;
        m_out[pt*3+2] = sz * inv;
    }
}

// ---------------------------------------------------------------------------
// fc_pos folded with mean-over-k -> fp16 K-major X[j][c], width 256.
// ---------------------------------------------------------------------------
__global__ __launch_bounds__(256) void fcpos_kernel(const float* __restrict__ pts,
                                                    const float* __restrict__ m_buf,
                                                    const float* __restrict__ W,
                                                    f16* __restrict__ X)
{
    const int pt = blockIdx.x;
    const int c  = threadIdx.x;
    float px = pts[pt*3+0], py = pts[pt*3+1], pz = pts[pt*3+2];
    float mx = m_buf[pt*3+0], my = m_buf[pt*3+1], mz = m_buf[pt*3+2];
    float w0 = W[c*3+0], w1 = W[c*3+1], w2 = W[c*3+2];
    float cx = my*pz - mz*py;
    float cy = mz*px - mx*pz;
    float cz = mx*py - my*px;
    float o0 = w0*(mx-px) + w1*px + w2*cx;
    float o1 = w0*(my-py) + w1*py + w2*cy;
    float o2 = w0*(mz-pz) + w1*pz + w2*cz;
    size_t base = (size_t)(pt*3) * 256 + c;
    X[base      ] = (f16)o0;
    X[base + 256] = (f16)o1;
    X[base + 512] = (f16)o2;
}

__global__ __launch_bounds__(256) void zero_nm(float* __restrict__ p, int n)
{
    int i = blockIdx.x*256 + threadIdx.x;
    if (i < n) p[i] = 0.f;
}

// ---------------------------------------------------------------------------
// MFMA GEMM: A-frags from L2 (swizzled global), B staged once in LDS.
// Block: 128 thr = 2 waves, block-tile 64(M) x 96(J); wave tile 64x48.
// grid = (JD/96=256, M/64). Split weights: hi + lo/1024 dual accumulators.
// Dual-K: phase2 re-stages B2 and switches A to (Aoff2, NKF2).
// mode 0: plain fp16 transposed store Out[j][m].
// mode 1: VN-ReLU epilogue (x from Xsrc/nm broadcast), write y.
// mode 2: plain store + fused mean-pool (atomicAdd into nm_acc).
// ---------------------------------------------------------------------------
__global__ __launch_bounds__(128, 2) void gemm_k(
    const u16* __restrict__ Wswz,
    int Aoff1, int NKF1, int K1, const f16* __restrict__ B1, int B1w,
    int Aoff2, int NKF2, int K2, const f16* __restrict__ B2,
    const f16* __restrict__ nm_h,
    f16* __restrict__ Out, int OutW,
    const f16* __restrict__ Xsrc, int Xw,
    int mode, float* __restrict__ nm_acc)
{
    __shared__ union {
        f16   B[96*264];      // [j][k] stride 264 (2-way banks, free) ~50.7KB
        float C[96*68];       // epilogue transpose: [j][m(64)+pad]
    } lds;

    const int tid  = threadIdx.x;
    const int jb   = blockIdx.x * 96;
    const int ob   = blockIdx.y * 64;
    const int lane = tid & 63;
    const int wv   = tid >> 6;            // 0..1
    const int qn   = wv * 48;
    const int l15  = lane & 15;
    const int lq8  = (lane >> 4) * 8;
    const int bB   = jb / 6144;           // batch of this j-tile (uniform)
    const f16* Whi = (const f16*)Wswz;
    const f16* Wlo = Whi + WTOT;

    floatx4 acc[4][3], accL[4][3];
#pragma unroll
    for (int fm = 0; fm < 4; ++fm)
#pragma unroll
        for (int fj = 0; fj < 3; ++fj) {
            acc[fm][fj]  = (floatx4){0.f,0.f,0.f,0.f};
            accL[fm][fj] = (floatx4){0.f,0.f,0.f,0.f};
        }

    const int mfg0 = ob >> 4;             // first m-frag index of this block

#pragma unroll 1
    for (int phase = 0; phase < 2; ++phase) {
        const f16* Bp; int Bw, Kp, Aoff, NKF;
        const f16* nmp = nullptr;
        if (phase == 0) { Bp = B1; Bw = B1w; Kp = K1; Aoff = Aoff1; NKF = NKF1; nmp = nm_h; }
        else            { if (K2 == 0) break; Bp = B2; Bw = K2; Kp = K2; Aoff = Aoff2; NKF = NKF2; }
        if (phase == 1) __syncthreads();          // prev MFMA readers done

        // stage B: 96 rows x Kp cols (uint4 = 8 f16); total = 96 * (Kp/8)
        const int ks = (Kp == 256) ? 5 : 4;       // log2(chunks per row)
        const int total = 12 * Kp;                // 96 * Kp / 8
#pragma unroll 1
        for (int idx = tid; idx < total; idx += 128) {
            int r  = idx >> ks;
            int c8 = (idx & ((1 << ks) - 1)) << 3;
            uint4 v;
            if (c8 < Bw) {
                v = *(const uint4*)(Bp + (size_t)(jb + r) * Bw + c8);
            } else {
                int v3 = (jb + r) % 3;
                v = *(const uint4*)(nmp + (bB*3 + v3)*128 + (c8 - Bw));
            }
            *(uint4*)&lds.B[r*264 + c8] = v;
        }
        __syncthreads();

        const int NK = Kp >> 5;
        half8 Aa[8], Ab[8];
        // load frags for kf: index fm*2+pl
#define LOADA(dst, kf_)                                                        \
        {                                                                      \
            int kf__ = (kf_);                                                  \
            _Pragma("unroll")                                                  \
            for (int fm = 0; fm < 4; ++fm) {                                   \
                size_t fo = ((size_t)((mfg0 + fm)*NKF + kf__)*64 + lane)*8;    \
                dst[fm*2+0] = *(const half8*)(Whi + Aoff + fo);                \
                dst[fm*2+1] = *(const half8*)(Wlo + Aoff + fo);                \
            }                                                                  \
        }
#define MMSTEP(af, kf_)                                                        \
        {                                                                      \
            int kf__ = (kf_);                                                  \
            half8 bq[3];                                                       \
            _Pragma("unroll")                                                  \
            for (int fj = 0; fj < 3; ++fj)                                     \
                bq[fj] = *(const half8*)&lds.B[(qn + fj*16 + l15)*264 + kf__*32 + lq8]; \
            _Pragma("unroll")                                                  \
            for (int fm = 0; fm < 4; ++fm)                                     \
                _Pragma("unroll")                                              \
                for (int fj = 0; fj < 3; ++fj) {                               \
                    acc[fm][fj]  = __builtin_amdgcn_mfma_f32_16x16x32_f16(af[fm*2+0], bq[fj], acc[fm][fj], 0, 0, 0);  \
                    accL[fm][fj] = __builtin_amdgcn_mfma_f32_16x16x32_f16(af[fm*2+1], bq[fj], accL[fm][fj], 0, 0, 0); \
                }                                                              \
        }
        LOADA(Aa, 0);
#pragma unroll 1
        for (int kf = 0; kf < NK; kf += 2) {
            LOADA(Ab, kf + 1);
            MMSTEP(Aa, kf);
            if (kf + 2 < NK) LOADA(Aa, kf + 2);
            MMSTEP(Ab, kf + 1);
        }
#undef LOADA
#undef MMSTEP
    }

    // recombine split-weight passes
    floatx4 res[4][3];
#pragma unroll
    for (int fm = 0; fm < 4; ++fm)
#pragma unroll
        for (int fj = 0; fj < 3; ++fj)
#pragma unroll
            for (int r = 0; r < 4; ++r)
                res[fm][fj][r] = acc[fm][fj][r] + accL[fm][fj][r] * (1.0f/1024.0f);

    // C/D layout: col(j) = lane&15, row(m) = (lane>>4)*4 + reg
    if (mode == 0 || mode == 2) {
#pragma unroll
        for (int fm = 0; fm < 4; ++fm)
#pragma unroll
            for (int fj = 0; fj < 3; ++fj) {
                int m0 = ob + fm*16 + (lane >> 4)*4;
                int j  = jb + qn + fj*16 + l15;
                u16 hh[4];
#pragma unroll
                for (int r = 0; r < 4; ++r) { f16 hv = (f16)res[fm][fj][r]; hh[r] = *(u16*)&hv; }
                uint2 pv;
                pv.x = (u32)hh[0] | ((u32)hh[1] << 16);
                pv.y = (u32)hh[2] | ((u32)hh[3] << 16);
                *(uint2*)(Out + (size_t)j * OutW + m0) = pv;
            }
    }
    if (mode == 1 || mode == 2) {
        __syncthreads();                          // all waves done with lds.B
#pragma unroll
        for (int fm = 0; fm < 4; ++fm)
#pragma unroll
            for (int fj = 0; fj < 3; ++fj) {
                int ml = fm*16 + (lane >> 4)*4;
                int jl = qn + fj*16 + l15;
                *(floatx4*)&lds.C[jl*68 + ml] = res[fm][fj];
            }
        __syncthreads();
        if (mode == 1) {
            // 32 points x 64 channels per block
#pragma unroll 1
            for (int it = 0; it < 16; ++it) {
                int idx = tid + 128*it;           // 0..2047
                int pt = idx >> 6;
                int ch = idx & 63;
                int m  = ob + ch;
                float d0 = lds.C[(pt*3+0)*68 + ch];
                float d1 = lds.C[(pt*3+1)*68 + ch];
                float d2 = lds.C[(pt*3+2)*68 + ch];
                int j0 = jb + pt*3;
                float x0, x1, x2;
                if (m < Xw) {
                    x0 = (float)Xsrc[(size_t)(j0+0)*Xw + m];
                    x1 = (float)Xsrc[(size_t)(j0+1)*Xw + m];
                    x2 = (float)Xsrc[(size_t)(j0+2)*Xw + m];
                } else {
                    x0 = (float)nm_h[(bB*3+0)*128 + m - Xw];
                    x1 = (float)nm_h[(bB*3+1)*128 + m - Xw];
                    x2 = (float)nm_h[(bB*3+2)*128 + m - Xw];
                }
                float dot = x0*d0 + x1*d1 + x2*d2;
                float y0, y1, y2;
                if (dot >= 0.f) { y0 = x0; y1 = x1; y2 = x2; }
                else {
                    float dsq = d0*d0 + d1*d1 + d2*d2 + 1e-8f;
                    float s = dot / dsq;
                    y0 = x0 - s*d0; y1 = x1 - s*d1; y2 = x2 - s*d2;
                }
                Out[(size_t)(j0+0)*OutW + m] = (f16)y0;
                Out[(size_t)(j0+1)*OutW + m] = (f16)y1;
                Out[(size_t)(j0+2)*OutW + m] = (f16)y2;
            }
        } else {
            // fused pool: sum over the 32 points for each (v, ch)
#pragma unroll 1
            for (int it = 0; it < 2; ++it) {
                int idx = tid + 128*it;           // 0..255; need 192
                if (idx < 192) {
                    int v = idx >> 6;
                    int ch = idx & 63;
                    float s = 0.f;
#pragma unroll 1
                    for (int pt = 0; pt < 32; ++pt) s += lds.C[(pt*3+v)*68 + ch];
                    atomicAdd(nm_acc + (bB*3+v)*128 + (ob + ch), s);
                }
            }
        }
    }
}

__global__ __launch_bounds__(256) void reduce_kernel(const float* __restrict__ nm_acc,
                                                     float* __restrict__ nm_f,
                                                     f16* __restrict__ nm_h)
{
    int i = blockIdx.x*256 + threadIdx.x;
    if (i >= 1536) return;
    float s = nm_acc[i] * (1.0f/2048.0f);
    nm_f[i] = s;
    nm_h[i] = (f16)s;
}

// ---------------------------------------------------------------------------
// Final head: d = act_d @ nm_b, VN-ReLU, out = fc_c @ y. fp32 throughout.
// ---------------------------------------------------------------------------
__global__ __launch_bounds__(128) void final_kernel(const float* __restrict__ nm_f,
                                                    const float* __restrict__ act_d,
                                                    const float* __restrict__ fc_c,
                                                    float* __restrict__ out)
{
    const int b = blockIdx.x;
    const int c = threadIdx.x;
    __shared__ float xs[128][3];
    __shared__ float ys[128][3];
    xs[c][0] = nm_f[(b*3+0)*128 + c];
    xs[c][1] = nm_f[(b*3+1)*128 + c];
    xs[c][2] = nm_f[(b*3+2)*128 + c];
    __syncthreads();
    float d0 = 0.f, d1 = 0.f, d2 = 0.f;
    for (int i = 0; i < 128; ++i) {
        float w = act_d[c*128 + i];
        d0 = fmaf(w, xs[i][0], d0);
        d1 = fmaf(w, xs[i][1], d1);
        d2 = fmaf(w, xs[i][2], d2);
    }
    float x0 = xs[c][0], x1 = xs[c][1], x2 = xs[c][2];
    float dot = x0*d0 + x1*d1 + x2*d2;
    float y0, y1, y2;
    if (dot >= 0.f) { y0 = x0; y1 = x1; y2 = x2; }
    else {
        float dsq = d0*d0 + d1*d1 + d2*d2 + 1e-8f;
        float s = dot / dsq;
        y0 = x0 - s*d0; y1 = x1 - s*d1; y2 = x2 - s*d2;
    }
    ys[c][0] = y0; ys[c][1] = y1; ys[c][2] = y2;
    __syncthreads();
    float o0 = 0.f, o1 = 0.f, o2 = 0.f;
    for (int i = 0; i < 128; ++i) {
        float w = fc_c[c*128 + i];
        o0 = fmaf(w, ys[i][0], o0);
        o1 = fmaf(w, ys[i][1], o1);
        o2 = fmaf(w, ys[i][2], o2);
    }
    out[b*384 + c*3 + 0] = o0;
    out[b*384 + c*3 + 1] = o1;
    out[b*384 + c*3 + 2] = o2;
}

// ---------------------------------------------------------------------------
extern "C" void kernel_launch(void* const* d_in, const int* in_sizes, int n_in,
                              void* d_out, int out_size, void* d_ws, size_t ws_size,
                              hipStream_t stream)
{
    const float* p      = (const float*)d_in[0];
    const float* fc_pos = (const float*)d_in[1];
    const float* bd0    = (const float*)d_in[2];
    const float* bW0    = (const float*)d_in[3];
    const float* bd1    = (const float*)d_in[4];
    const float* bW1    = (const float*)d_in[5];
    const float* bWs    = (const float*)d_in[6];
    const float* fc_c   = (const float*)d_in[7];
    const float* act_d  = (const float*)d_in[8];
    float* out = (float*)d_out;

    // Workspace layout (16B-aligned)
    char* w = (char*)d_ws;
    float* m_buf  = (float*)w;  w += 98304;                  // [8192*3] f32
    float* nm_acc = (float*)w;  w += 5*1536*4;               // per-iter pool sums
    float* nm_f   = (float*)w;  w += 6144;
    f16*   nm_h   = (f16*)w;    w += 3072 + 1024;
    u16*   Wswz   = (u16*)w;    w += (size_t)2*WTOT*2;       // swizzled split weights
    f16*   Xa     = (f16*)w;    w += (size_t)JD*256*2;       // fcpos out (width 256)
    f16*   T      = (f16*)w;    w += (size_t)JD*256*2;       // y (width 256)
    f16*   H      = (f16*)w;    w += (size_t)JD*128*2;       // h
    f16*   T2     = (f16*)w;    w += (size_t)JD*128*2;       // y2
    f16*   netA   = (f16*)w;    w += (size_t)JD*128*2;       // net ping
    f16*   netB   = (f16*)w;    w += (size_t)JD*128*2;       // net pong

    convert_w<<<dim3((WTOT+255)/256), dim3(256), 0, stream>>>(bd0, bW0, bd1, bW1, bWs, Wswz);
    zero_nm<<<dim3(30), dim3(256), 0, stream>>>(nm_acc, 5*1536);
    knn_kernel<<<dim3(1024), dim3(256), 0, stream>>>(p, m_buf);
    fcpos_kernel<<<dim3(P_TOT), dim3(256), 0, stream>>>(p, m_buf, fc_pos, Xa);

    f16* netIn = netA;
    f16* netOut = netB;
    for (int blk = 0; blk < 5; ++blk) {
        const int offD0 = blk*65536;
        const int offW0 = 327680 + blk*32768;
        const int offD1 = 491520 + blk*16384;
        const int offW1 = 573440 + blk*16384;
        const int offWs = 655360 + blk*32768;

        const f16* xin = (blk == 0) ? Xa : netIn;
        const int  xw  = (blk == 0) ? 256 : 128;
        const f16* nmb = (blk == 0) ? nullptr : nm_h;

        // y = vnrelu(x, D0@x) -> T (width 256)
        gemm_k<<<dim3(256, 4), dim3(128), 0, stream>>>(
            Wswz, offD0, 8, 256, xin, xw, 0, 0, 0, nullptr, nmb,
            T, 256, xin, xw, 1, nullptr);
        // h = W0 @ y -> H (width 128)
        gemm_k<<<dim3(256, 2), dim3(128), 0, stream>>>(
            Wswz, offW0, 8, 256, T, 256, 0, 0, 0, nullptr, nullptr,
            H, 128, nullptr, 0, 0, nullptr);
        // y2 = vnrelu(h, D1@h) -> T2 (width 128)
        gemm_k<<<dim3(256, 2), dim3(128), 0, stream>>>(
            Wswz, offD1, 4, 128, H, 128, 0, 0, 0, nullptr, nullptr,
            T2, 128, H, 128, 1, nullptr);
        // net = Ws@x + W1@y2 -> netOut (width 128), fused pool
        gemm_k<<<dim3(256, 2), dim3(128), 0, stream>>>(
            Wswz, offWs, 8, 256, xin, xw, offW1, 4, 128, T2, nmb,
            netOut, 128, nullptr, 0, 2, nm_acc + blk*1536);
        // pooled mean for next block (and final head after blk 4)
        reduce_kernel<<<dim3(6), dim3(256), 0, stream>>>(nm_acc + blk*1536, nm_f, nm_h);

        f16* tmp = netIn; netIn = netOut; netOut = tmp;
    }

    final_kernel<<<dim3(4), dim3(128), 0, stream>>>(nm_f, act_d, fc_c, out);

    (void)in_sizes; (void)n_in; (void)out_size; (void)ws_size;
}

// Round 8
// 281.634 us; speedup vs baseline: 5.1487x; 2.0381x over previous
//
#include <hip/hip_runtime.h>
#include <math.h>

#define N_PTS 2048
#define K_NN  20
#define WTOT  819200          // total weight elements across the 5 tensors

typedef unsigned short u16;
typedef unsigned int   u32;
typedef _Float16 f16;
using half8   = __attribute__((ext_vector_type(8))) _Float16;
using floatx4 = __attribute__((ext_vector_type(4))) float;

// Weights: split fp16.  w ~= hi + lo/1024, |err| ~ 2^-24 |w|.
__device__ __forceinline__ void split2h(float v, f16& h, f16& l) {
    h = (f16)v;
    l = (f16)((v - (float)h) * 1024.0f);
}

// ---------------------------------------------------------------------------
// Weight conversion + MFMA-fragment swizzle (same layout as round 7, verified).
// frag (mf,kf) = 64 lanes x 8 f16 contiguous; lane q*16+r holds A[mf*16+r][kf*32+q*8+i].
// Also zeroes nm_acc (5*1536 floats) every launch (graph-replay safe).
// ---------------------------------------------------------------------------
__global__ __launch_bounds__(256) void convert_w(
    const float* __restrict__ bd0, const float* __restrict__ bW0,
    const float* __restrict__ bd1, const float* __restrict__ bW1,
    const float* __restrict__ bWs, u16* __restrict__ Wswz,
    float* __restrict__ nm_acc)
{
    int i = blockIdx.x * 256 + threadIdx.x;
    if (i >= WTOT) return;
    if (i < 7680) nm_acc[i] = 0.f;
    float v; int base, K, local;
    if (i < 327680)      { int rel = i;          base = (rel/65536)*65536;            local = rel%65536; K = 256; v = bd0[rel]; }
    else if (i < 491520) { int rel = i - 327680; base = 327680 + (rel/32768)*32768;   local = rel%32768; K = 256; v = bW0[rel]; }
    else if (i < 573440) { int rel = i - 491520; base = 491520 + (rel/16384)*16384;   local = rel%16384; K = 128; v = bd1[rel]; }
    else if (i < 655360) { int rel = i - 573440; base = 573440 + (rel/16384)*16384;   local = rel%16384; K = 128; v = bW1[rel]; }
    else                 { int rel = i - 655360; base = 655360 + (rel/32768)*32768;   local = rel%32768; K = 256; v = bWs[rel]; }
    int m = local / K, k = local % K;
    int NKF = K >> 5;
    int mf = m >> 4, r = m & 15;
    int kf = k >> 5, q = (k >> 3) & 3, ii = k & 7;
    int lane = q*16 + r;
    int dst = base + ((mf*NKF + kf)*64 + lane)*8 + ii;
    f16 h, l; split2h(v, h, l);
    f16* W = (f16*)Wswz;
    W[dst] = h; W[WTOT + dst] = l;
}

// nd must be bit-identical in phase 1 and phase 2b.
__device__ __forceinline__ float neg_dist(float4 q2, float4 c) {
    return fmaf(q2.x, c.x, fmaf(q2.y, c.y, fmaf(q2.z, c.z, -q2.w))) - c.w;
}

// ---------------------------------------------------------------------------
// KNN (unchanged from round 7, verified): 1024 blocks x 256 thr.
// ---------------------------------------------------------------------------
__global__ __launch_bounds__(256) void knn_kernel(const float* __restrict__ pts,
                                                  float* __restrict__ m_out)
{
    __shared__ float4 sp[N_PTS];                      // 32 KB
    const int b     = blockIdx.x >> 8;
    const int qbase = (blockIdx.x & 255) << 3;
    const int ql    = threadIdx.x >> 5;
    const int sl    = threadIdx.x & 31;
    const float* pb = pts + (size_t)b * N_PTS * 3;
    for (int i = threadIdx.x; i < N_PTS; i += 256) {
        float x = pb[i*3+0], y = pb[i*3+1], z = pb[i*3+2];
        sp[i] = make_float4(x, y, z, x*x + y*y + z*z);
    }
    __syncthreads();

    const int n = qbase + ql;
    const float4 q = sp[n];
    const float4 q2 = make_float4(2.f*q.x, 2.f*q.y, 2.f*q.z, q.w);

    float t[K_NN];
#pragma unroll
    for (int s = 0; s < K_NN; ++s) t[s] = -INFINITY;

    for (int j = 0; j < N_PTS/32; ++j) {
        float4 c = sp[j*32 + sl];
        float v = neg_dist(q2, c);
#pragma unroll
        for (int s = 0; s < K_NN; ++s) {
            float nx = (s < K_NN-1) ? t[s+1] : INFINITY;
            t[s] = fminf(fmaxf(t[s], v), nx);
        }
    }

    float head = t[K_NN-1];
    float T = -INFINITY;
#pragma unroll 1
    for (int e = 0; e < K_NN; ++e) {
        float v = head; int w = sl;
#pragma unroll
        for (int off = 1; off < 32; off <<= 1) {
            float vo = __shfl_xor(v, off);
            int   wo = __shfl_xor(w, off);
            bool take = (vo > v) || (vo == v && wo < w);
            v = take ? vo : v;
            w = take ? wo : w;
        }
        T = v;
        if (w == sl) {
#pragma unroll
            for (int s = K_NN-1; s > 0; --s) t[s] = t[s-1];
            t[0] = -INFINITY;
            head = t[K_NN-1];
        }
    }

    float sx = 0.f, sy = 0.f, sz = 0.f;
    for (int j = 0; j < N_PTS/32; ++j) {
        float4 c = sp[j*32 + sl];
        float v = neg_dist(q2, c);
        if (v >= T) { sx += c.x; sy += c.y; sz += c.z; }
    }
#pragma unroll
    for (int off = 1; off < 32; off <<= 1) {
        sx += __shfl_xor(sx, off);
        sy += __shfl_xor(sy, off);
        sz += __shfl_xor(sz, off);
    }
    if (sl == 0) {
        const float inv = 1.0f / (float)K_NN;
        const int pt = b * N_PTS + n;
        m_out[pt*3+0] = sx * inv;
        m_out[pt*3+1] = sy * inv;
        m_out[pt*3+2] = sz * inv;
    }
}

// ---------------------------------------------------------------------------
// Templated MFMA GEMM core: A-frags from L2 (swizzled), B from LDS.
// MF m-frags x JF j-frags per wave, split weights via dual accumulators.
// ---------------------------------------------------------------------------
template<int MF, int JF>
__device__ __forceinline__ void run_gemm(
    const f16* __restrict__ Whi, const f16* __restrict__ Wlo, size_t aoff,
    int NKF, int NK, const f16* Blds, int bstride, int lane,
    floatx4 (&acc)[MF][JF], floatx4 (&accL)[MF][JF])
{
    const int l15 = lane & 15;
    const int lq8 = (lane >> 4) * 8;
    half8 Aa[2*MF], Ab[2*MF];

    auto loada = [&](half8* dst, int kf) {
#pragma unroll
        for (int fm = 0; fm < MF; ++fm) {
            size_t fo = aoff + (size_t)(fm*NKF + kf)*512 + (size_t)lane*8;
            dst[fm*2+0] = *(const half8*)(Whi + fo);
            dst[fm*2+1] = *(const half8*)(Wlo + fo);
        }
    };
    auto step = [&](half8* af, int kf) {
        half8 bq[JF];
#pragma unroll
        for (int fj = 0; fj < JF; ++fj)
            bq[fj] = *(const half8*)&Blds[(fj*16 + l15)*bstride + kf*32 + lq8];
#pragma unroll
        for (int fm = 0; fm < MF; ++fm)
#pragma unroll
            for (int fj = 0; fj < JF; ++fj) {
                acc[fm][fj]  = __builtin_amdgcn_mfma_f32_16x16x32_f16(af[fm*2+0], bq[fj], acc[fm][fj], 0, 0, 0);
                accL[fm][fj] = __builtin_amdgcn_mfma_f32_16x16x32_f16(af[fm*2+1], bq[fj], accL[fm][fj], 0, 0, 0);
            }
    };

    loada(Aa, 0);
#pragma unroll 1
    for (int kf = 0; kf < NK; kf += 2) {
        loada(Ab, kf + 1);
        step(Aa, kf);
        if (kf + 2 < NK) loada(Aa, kf + 2);
        step(Ab, kf + 1);
    }
}

__device__ __forceinline__ uint2 pack_res(floatx4 a, floatx4 aL) {
    u16 hh[4];
#pragma unroll
    for (int r = 0; r < 4; ++r) {
        f16 hv = (f16)(a[r] + aL[r] * (1.0f/1024.0f));
        hh[r] = *(u16*)&hv;
    }
    uint2 pv;
    pv.x = (u32)hh[0] | ((u32)hh[1] << 16);
    pv.y = (u32)hh[2] | ((u32)hh[3] << 16);
    return pv;
}

// ---------------------------------------------------------------------------
// Fused resnet block: one dispatch does D0->relu->W0->D1->relu->(Ws||W1)+pool.
// grid 512 blocks (48 j-cols = 16 points each), 256 thr (4 waves), 63.7KB LDS,
// 2 blocks/CU. Intermediates live entirely in LDS.
// ---------------------------------------------------------------------------
__global__ __launch_bounds__(256, 2) void resblk_kernel(
    const u16* __restrict__ Wswz,
    int offD0, int offW0, int offD1, int offW1, int offWs,
    const f16* __restrict__ netIn, const float* __restrict__ nm_prev,
    const float* __restrict__ pts, const float* __restrict__ m_buf,
    const float* __restrict__ fcW,
    f16* __restrict__ netOut, float* __restrict__ nm_out, int blk0)
{
    __shared__ struct {
        f16 X[48*264];                              // x (width 256), 25344 B
        union { f16 d[48*264]; float C[48*132]; } Y;// d/y | d1 | float-C scratch
        f16 H[48*136];                              // h / y2 (width 128)
    } s;

    const int tid  = threadIdx.x;
    const int jb   = blockIdx.x * 48;
    const int bB   = blockIdx.x >> 7;               // batch (128 blocks/batch)
    const int lane = tid & 63;
    const int wv   = tid >> 6;                      // 0..3
    const f16* Whi = (const f16*)Wswz;
    const f16* Wlo = Whi + WTOT;

    // ---- stage x into LDS ------------------------------------------------
    if (blk0) {
        float* Hf = (float*)s.H;                    // temp: W(768) p(48)@768 m(48)@816
        const int ptbase = blockIdx.x * 16;
        for (int i = tid; i < 768; i += 256) Hf[i] = fcW[i];
        if (tid < 96) Hf[768 + tid] = (tid < 48) ? pts[ptbase*3 + tid]
                                                 : m_buf[ptbase*3 + tid - 48];
        __syncthreads();
#pragma unroll 1
        for (int it = 0; it < 6; ++it) {
            int idx = tid + 256*it;                 // 0..1535
            int r = idx >> 5;                       // j-row 0..47
            int cg = idx & 31;
            int l = r / 3, v = r - l*3;
            float p0 = Hf[768+l*3], p1 = Hf[768+l*3+1], p2 = Hf[768+l*3+2];
            float m0 = Hf[816+l*3], m1 = Hf[816+l*3+1], m2 = Hf[816+l*3+2];
            float pv[3] = {p0,p1,p2}, mv[3] = {m0,m1,m2};
            int v1 = (v==2) ? 0 : v+1;
            int v2 = (v==0) ? 2 : v-1;
            float av = mv[v] - pv[v];
            float bv = pv[v];
            float cv = mv[v1]*pv[v2] - mv[v2]*pv[v1];
            half8 o;
#pragma unroll
            for (int k = 0; k < 8; ++k) {
                int ch = cg*8 + k;
                o[k] = (f16)(Hf[ch*3+0]*av + Hf[ch*3+1]*bv + Hf[ch*3+2]*cv);
            }
            *(half8*)&s.X[r*264 + cg*8] = o;
        }
    } else {
#pragma unroll 1
        for (int it = 0; it < 6; ++it) {
            int idx = tid + 256*it;
            int r = idx >> 5;
            int cg = idx & 31;
            if (cg < 16) {
                uint4 vv = *(const uint4*)(netIn + (size_t)(jb + r)*128 + cg*8);
                *(uint4*)&s.X[r*264 + cg*8] = vv;
            } else {
                int v = r % 3;                      // jb % 3 == 0
                const float* np = nm_prev + (bB*3+v)*128 + (cg-16)*8;
                half8 o;
#pragma unroll
                for (int k = 0; k < 8; ++k) o[k] = (f16)(np[k] * (1.0f/2048.0f));
                *(half8*)&s.X[r*264 + cg*8] = o;
            }
        }
    }
    __syncthreads();

    // ---- gemm1: d = D0 @ x  (M=256, K=256), wave -> m-chunk 64 -----------
    {
        floatx4 acc[4][3], accL[4][3];
#pragma unroll
        for (int a = 0; a < 4; ++a)
#pragma unroll
            for (int b = 0; b < 3; ++b) { acc[a][b] = (floatx4){0,0,0,0}; accL[a][b] = (floatx4){0,0,0,0}; }
        run_gemm<4,3>(Whi, Wlo, (size_t)offD0 + (size_t)wv*16384, 8, 8, s.X, 264, lane, acc, accL);
#pragma unroll
        for (int fm = 0; fm < 4; ++fm)
#pragma unroll
            for (int fj = 0; fj < 3; ++fj) {
                int mloc = wv*64 + fm*16 + (lane>>4)*4;
                int jl   = fj*16 + (lane & 15);
                *(uint2*)&s.Y.d[jl*264 + mloc] = pack_res(acc[fm][fj], accL[fm][fj]);
            }
    }
    __syncthreads();

    // ---- relu1: y = vnrelu(x, d), width 256, in-place in Y ---------------
#pragma unroll 1
    for (int it = 0; it < 2; ++it) {
        int idx = tid + 256*it;                     // 0..511
        int l = idx >> 5, cg = idx & 31;
        half8 xa = *(const half8*)&s.X[(l*3+0)*264 + cg*8];
        half8 xb = *(const half8*)&s.X[(l*3+1)*264 + cg*8];
        half8 xc = *(const half8*)&s.X[(l*3+2)*264 + cg*8];
        half8 da = *(const half8*)&s.Y.d[(l*3+0)*264 + cg*8];
        half8 db = *(const half8*)&s.Y.d[(l*3+1)*264 + cg*8];
        half8 dc = *(const half8*)&s.Y.d[(l*3+2)*264 + cg*8];
        half8 ya, yb, yc;
#pragma unroll
        for (int k = 0; k < 8; ++k) {
            float x0 = (float)xa[k], x1 = (float)xb[k], x2 = (float)xc[k];
            float d0 = (float)da[k], d1 = (float)db[k], d2 = (float)dc[k];
            float dot = x0*d0 + x1*d1 + x2*d2;
            float y0, y1, y2;
            if (dot >= 0.f) { y0 = x0; y1 = x1; y2 = x2; }
            else {
                float dsq = d0*d0 + d1*d1 + d2*d2 + 1e-8f;
                float sc = dot / dsq;
                y0 = x0 - sc*d0; y1 = x1 - sc*d1; y2 = x2 - sc*d2;
            }
            ya[k] = (f16)y0; yb[k] = (f16)y1; yc[k] = (f16)y2;
        }
        *(half8*)&s.Y.d[(l*3+0)*264 + cg*8] = ya;
        *(half8*)&s.Y.d[(l*3+1)*264 + cg*8] = yb;
        *(half8*)&s.Y.d[(l*3+2)*264 + cg*8] = yc;
    }
    __syncthreads();

    // ---- gemm2: h = W0 @ y (M=128, K=256), wave -> m-chunk 32 ------------
    {
        floatx4 acc[2][3], accL[2][3];
#pragma unroll
        for (int a = 0; a < 2; ++a)
#pragma unroll
            for (int b = 0; b < 3; ++b) { acc[a][b] = (floatx4){0,0,0,0}; accL[a][b] = (floatx4){0,0,0,0}; }
        run_gemm<2,3>(Whi, Wlo, (size_t)offW0 + (size_t)wv*8192, 8, 8, s.Y.d, 264, lane, acc, accL);
#pragma unroll
        for (int fm = 0; fm < 2; ++fm)
#pragma unroll
            for (int fj = 0; fj < 3; ++fj) {
                int mloc = wv*32 + fm*16 + (lane>>4)*4;
                int jl   = fj*16 + (lane & 15);
                *(uint2*)&s.H[jl*136 + mloc] = pack_res(acc[fm][fj], accL[fm][fj]);
            }
    }
    __syncthreads();

    // ---- gemm3: d1 = D1 @ h (M=128, K=128) -> Y region, stride 136 -------
    {
        floatx4 acc[2][3], accL[2][3];
#pragma unroll
        for (int a = 0; a < 2; ++a)
#pragma unroll
            for (int b = 0; b < 3; ++b) { acc[a][b] = (floatx4){0,0,0,0}; accL[a][b] = (floatx4){0,0,0,0}; }
        run_gemm<2,3>(Whi, Wlo, (size_t)offD1 + (size_t)wv*4096, 4, 4, s.H, 136, lane, acc, accL);
#pragma unroll
        for (int fm = 0; fm < 2; ++fm)
#pragma unroll
            for (int fj = 0; fj < 3; ++fj) {
                int mloc = wv*32 + fm*16 + (lane>>4)*4;
                int jl   = fj*16 + (lane & 15);
                *(uint2*)&s.Y.d[jl*136 + mloc] = pack_res(acc[fm][fj], accL[fm][fj]);
            }
    }
    __syncthreads();

    // ---- relu2: y2 = vnrelu(h, d1), width 128, write over H --------------
    {
        int l = tid >> 4, cg = tid & 15;
        half8 xa = *(const half8*)&s.H[(l*3+0)*136 + cg*8];
        half8 xb = *(const half8*)&s.H[(l*3+1)*136 + cg*8];
        half8 xc = *(const half8*)&s.H[(l*3+2)*136 + cg*8];
        half8 da = *(const half8*)&s.Y.d[(l*3+0)*136 + cg*8];
        half8 db = *(const half8*)&s.Y.d[(l*3+1)*136 + cg*8];
        half8 dc = *(const half8*)&s.Y.d[(l*3+2)*136 + cg*8];
        half8 ya, yb, yc;
#pragma unroll
        for (int k = 0; k < 8; ++k) {
            float x0 = (float)xa[k], x1 = (float)xb[k], x2 = (float)xc[k];
            float d0 = (float)da[k], d1 = (float)db[k], d2 = (float)dc[k];
            float dot = x0*d0 + x1*d1 + x2*d2;
            float y0, y1, y2;
            if (dot >= 0.f) { y0 = x0; y1 = x1; y2 = x2; }
            else {
                float dsq = d0*d0 + d1*d1 + d2*d2 + 1e-8f;
                float sc = dot / dsq;
                y0 = x0 - sc*d0; y1 = x1 - sc*d1; y2 = x2 - sc*d2;
            }
            ya[k] = (f16)y0; yb[k] = (f16)y1; yc[k] = (f16)y2;
        }
        __syncthreads();                            // all d1 reads before H overwrite? (reads above)
        *(half8*)&s.H[(l*3+0)*136 + cg*8] = ya;
        *(half8*)&s.H[(l*3+1)*136 + cg*8] = yb;
        *(half8*)&s.H[(l*3+2)*136 + cg*8] = yc;
    }
    __syncthreads();

    // ---- gemm4: net = Ws@x + W1@y2, store + fused pool -------------------
    {
        floatx4 acc[2][3], accL[2][3];
#pragma unroll
        for (int a = 0; a < 2; ++a)
#pragma unroll
            for (int b = 0; b < 3; ++b) { acc[a][b] = (floatx4){0,0,0,0}; accL[a][b] = (floatx4){0,0,0,0}; }
        run_gemm<2,3>(Whi, Wlo, (size_t)offWs + (size_t)wv*8192, 8, 8, s.X, 264, lane, acc, accL);
        run_gemm<2,3>(Whi, Wlo, (size_t)offW1 + (size_t)wv*4096, 4, 4, s.H, 136, lane, acc, accL);
#pragma unroll
        for (int fm = 0; fm < 2; ++fm)
#pragma unroll
            for (int fj = 0; fj < 3; ++fj) {
                int mloc = wv*32 + fm*16 + (lane>>4)*4;
                int jl   = fj*16 + (lane & 15);
                floatx4 res;
#pragma unroll
                for (int r = 0; r < 4; ++r) res[r] = acc[fm][fj][r] + accL[fm][fj][r] * (1.0f/1024.0f);
                u16 hh[4];
#pragma unroll
                for (int r = 0; r < 4; ++r) { f16 hv = (f16)res[r]; hh[r] = *(u16*)&hv; }
                uint2 pv;
                pv.x = (u32)hh[0] | ((u32)hh[1] << 16);
                pv.y = (u32)hh[2] | ((u32)hh[3] << 16);
                *(uint2*)(netOut + (size_t)(jb + jl)*128 + mloc) = pv;
                *(floatx4*)&s.Y.C[jl*132 + mloc] = res;
            }
    }
    __syncthreads();

    // ---- pool: sum over 16 points per (v, ch), atomic into nm_out --------
#pragma unroll 1
    for (int idx = tid; idx < 384; idx += 256) {
        int v = idx >> 7, ch = idx & 127;
        float sum = 0.f;
#pragma unroll 1
        for (int pt = 0; pt < 16; ++pt) sum += s.Y.C[(pt*3+v)*132 + ch];
        atomicAdd(nm_out + (bB*3+v)*128 + ch, sum);
    }
}

// ---------------------------------------------------------------------------
// Final head: reads raw pool sums (scale 1/2048). fp32 throughout.
// ---------------------------------------------------------------------------
__global__ __launch_bounds__(128) void final_kernel(const float* __restrict__ nm_sum,
                                                    const float* __restrict__ act_d,
                                                    const float* __restrict__ fc_c,
                                                    float* __restrict__ out)
{
    const int b = blockIdx.x;
    const int c = threadIdx.x;
    __shared__ float xs[128][3];
    __shared__ float ys[128][3];
    xs[c][0] = nm_sum[(b*3+0)*128 + c] * (1.0f/2048.0f);
    xs[c][1] = nm_sum[(b*3+1)*128 + c] * (1.0f/2048.0f);
    xs[c][2] = nm_sum[(b*3+2)*128 + c] * (1.0f/2048.0f);
    __syncthreads();
    float d0 = 0.f, d1 = 0.f, d2 = 0.f;
    for (int i = 0; i < 128; ++i) {
        float w = act_d[c*128 + i];
        d0 = fmaf(w, xs[i][0], d0);
        d1 = fmaf(w, xs[i][1], d1);
        d2 = fmaf(w, xs[i][2], d2);
    }
    float x0 = xs[c][0], x1 = xs[c][1], x2 = xs[c][2];
    float dot = x0*d0 + x1*d1 + x2*d2;
    float y0, y1, y2;
    if (dot >= 0.f) { y0 = x0; y1 = x1; y2 = x2; }
    else {
        float dsq = d0*d0 + d1*d1 + d2*d2 + 1e-8f;
        float sc = dot / dsq;
        y0 = x0 - sc*d0; y1 = x1 - sc*d1; y2 = x2 - sc*d2;
    }
    ys[c][0] = y0; ys[c][1] = y1; ys[c][2] = y2;
    __syncthreads();
    float o0 = 0.f, o1 = 0.f, o2 = 0.f;
    for (int i = 0; i < 128; ++i) {
        float w = fc_c[c*128 + i];
        o0 = fmaf(w, ys[i][0], o0);
        o1 = fmaf(w, ys[i][1], o1);
        o2 = fmaf(w, ys[i][2], o2);
    }
    out[b*384 + c*3 + 0] = o0;
    out[b*384 + c*3 + 1] = o1;
    out[b*384 + c*3 + 2] = o2;
}

// ---------------------------------------------------------------------------
extern "C" void kernel_launch(void* const* d_in, const int* in_sizes, int n_in,
                              void* d_out, int out_size, void* d_ws, size_t ws_size,
                              hipStream_t stream)
{
    const float* p      = (const float*)d_in[0];
    const float* fc_pos = (const float*)d_in[1];
    const float* bd0    = (const float*)d_in[2];
    const float* bW0    = (const float*)d_in[3];
    const float* bd1    = (const float*)d_in[4];
    const float* bW1    = (const float*)d_in[5];
    const float* bWs    = (const float*)d_in[6];
    const float* fc_c   = (const float*)d_in[7];
    const float* act_d  = (const float*)d_in[8];
    float* out = (float*)d_out;

    // Workspace layout (16B-aligned)
    char* w = (char*)d_ws;
    float* m_buf  = (float*)w;  w += 98304;                  // knn means [8192*3]
    float* nm_acc = (float*)w;  w += 5*1536*4;               // pool sums per block
    u16*   Wswz   = (u16*)w;    w += (size_t)2*WTOT*2;       // swizzled split weights
    f16*   netA   = (f16*)w;    w += (size_t)24576*128*2;
    f16*   netB   = (f16*)w;    w += (size_t)24576*128*2;

    convert_w<<<dim3(3200), dim3(256), 0, stream>>>(bd0, bW0, bd1, bW1, bWs, Wswz, nm_acc);
    knn_kernel<<<dim3(1024), dim3(256), 0, stream>>>(p, m_buf);

    f16* nIn = netA;
    f16* nOut = netB;
    for (int blk = 0; blk < 5; ++blk) {
        const int offD0 = blk*65536;
        const int offW0 = 327680 + blk*32768;
        const int offD1 = 491520 + blk*16384;
        const int offW1 = 573440 + blk*16384;
        const int offWs = 655360 + blk*32768;
        const float* nmp = (blk == 0) ? nullptr : (nm_acc + (blk-1)*1536);
        resblk_kernel<<<dim3(512), dim3(256), 0, stream>>>(
            Wswz, offD0, offW0, offD1, offW1, offWs,
            (blk == 0) ? netA : nIn, nmp, p, m_buf, fc_pos,
            nOut, nm_acc + blk*1536, (blk == 0) ? 1 : 0);
        f16* tmp = nIn; nIn = nOut; nOut = tmp;
    }

    final_kernel<<<dim3(4), dim3(128), 0, stream>>>(nm_acc + 4*1536, act_d, fc_c, out);

    (void)in_sizes; (void)n_in; (void)out_size; (void)ws_size;
}

// Round 9
// 242.355 us; speedup vs baseline: 5.9832x; 1.1621x over previous
//
#include <hip/hip_runtime.h>
#include <math.h>

#define N_PTS 2048
#define K_NN  20
#define K_D   10              // per-slice kept depth (exact up to 10-per-slice overlap)
#define WTOT  819200          // total weight elements across the 5 tensors

typedef unsigned short u16;
typedef unsigned int   u32;
typedef _Float16 f16;
using half8   = __attribute__((ext_vector_type(8))) _Float16;
using floatx4 = __attribute__((ext_vector_type(4))) float;

// Weights: split fp16.  w ~= hi + lo/1024, |err| ~ 2^-24 |w|.
__device__ __forceinline__ void split2h(float v, f16& h, f16& l) {
    h = (f16)v;
    l = (f16)((v - (float)h) * 1024.0f);
}

// nd must be bit-identical in phase 1 and phase 2b.
__device__ __forceinline__ float neg_dist(float4 q2, float4 c) {
    return fmaf(q2.x, c.x, fmaf(q2.y, c.y, fmaf(q2.z, c.z, -q2.w))) - c.w;
}

// ---------------------------------------------------------------------------
// prep_kernel = KNN (blocks 0..1023) + weight convert/swizzle (blocks 1024+).
// KNN: 8 queries/block, 32 slices/query, per-slice branchless sorted top-10;
// 20-pop cross-lane tournament -> exact T; rescan sums positions >= T.
// Convert: split fp16 + MFMA-fragment swizzle (frag = 64 lanes x 8 f16;
// lane q*16+r holds A[mf*16+r][kf*32+q*8+i]); also zeroes nm_acc.
// ---------------------------------------------------------------------------
__global__ __launch_bounds__(256) void prep_kernel(
    const float* __restrict__ pts, float* __restrict__ m_out,
    const float* __restrict__ bd0, const float* __restrict__ bW0,
    const float* __restrict__ bd1, const float* __restrict__ bW1,
    const float* __restrict__ bWs, u16* __restrict__ Wswz,
    float* __restrict__ nm_acc)
{
    __shared__ float4 sp[N_PTS];                      // 32 KB (knn branch only)
    if (blockIdx.x >= 1024) {
        int i = (blockIdx.x - 1024) * 256 + threadIdx.x;
        if (i >= WTOT) return;
        if (i < 7680) nm_acc[i] = 0.f;
        float v; int base, K, local;
        if (i < 327680)      { int rel = i;          base = (rel/65536)*65536;            local = rel%65536; K = 256; v = bd0[rel]; }
        else if (i < 491520) { int rel = i - 327680; base = 327680 + (rel/32768)*32768;   local = rel%32768; K = 256; v = bW0[rel]; }
        else if (i < 573440) { int rel = i - 491520; base = 491520 + (rel/16384)*16384;   local = rel%16384; K = 128; v = bd1[rel]; }
        else if (i < 655360) { int rel = i - 573440; base = 573440 + (rel/16384)*16384;   local = rel%16384; K = 128; v = bW1[rel]; }
        else                 { int rel = i - 655360; base = 655360 + (rel/32768)*32768;   local = rel%32768; K = 256; v = bWs[rel]; }
        int m = local / K, k = local % K;
        int NKF = K >> 5;
        int mf = m >> 4, r = m & 15;
        int kf = k >> 5, q = (k >> 3) & 3, ii = k & 7;
        int lane = q*16 + r;
        int dst = base + ((mf*NKF + kf)*64 + lane)*8 + ii;
        f16 h, l; split2h(v, h, l);
        f16* W = (f16*)Wswz;
        W[dst] = h; W[WTOT + dst] = l;
        return;
    }

    // ---- KNN ----
    const int b     = blockIdx.x >> 8;
    const int qbase = (blockIdx.x & 255) << 3;
    const int ql    = threadIdx.x >> 5;
    const int sl    = threadIdx.x & 31;
    const float* pb = pts + (size_t)b * N_PTS * 3;
    for (int i = threadIdx.x; i < N_PTS; i += 256) {
        float x = pb[i*3+0], y = pb[i*3+1], z = pb[i*3+2];
        sp[i] = make_float4(x, y, z, x*x + y*y + z*z);
    }
    __syncthreads();

    const int n = qbase + ql;
    const float4 q = sp[n];
    const float4 q2 = make_float4(2.f*q.x, 2.f*q.y, 2.f*q.z, q.w);

    float t[K_D];
#pragma unroll
    for (int s = 0; s < K_D; ++s) t[s] = -INFINITY;

    // Phase 1: branchless sorted top-10 of my 64 candidates
    for (int j = 0; j < N_PTS/32; ++j) {
        float4 c = sp[j*32 + sl];
        float v = neg_dist(q2, c);
#pragma unroll
        for (int s = 0; s < K_D; ++s) {
            float nx = (s < K_D-1) ? t[s+1] : INFINITY;
            t[s] = fminf(fmaxf(t[s], v), nx);
        }
    }

    // Phase 2a: pop 20 maxima across the 32 slices; T = the 20th.
    float head = t[K_D-1];
    float T = -INFINITY;
#pragma unroll 1
    for (int e = 0; e < K_NN; ++e) {
        float v = head; int w = sl;
#pragma unroll
        for (int off = 1; off < 32; off <<= 1) {
            float vo = __shfl_xor(v, off);
            int   wo = __shfl_xor(w, off);
            bool take = (vo > v) || (vo == v && wo < w);
            v = take ? vo : v;
            w = take ? wo : w;
        }
        T = v;
        if (w == sl) {
#pragma unroll
            for (int s = K_D-1; s > 0; --s) t[s] = t[s-1];
            t[0] = -INFINITY;
            head = t[K_D-1];
        }
    }

    // Phase 2b: rescan, sum positions with nd >= T
    float sx = 0.f, sy = 0.f, sz = 0.f;
    for (int j = 0; j < N_PTS/32; ++j) {
        float4 c = sp[j*32 + sl];
        float v = neg_dist(q2, c);
        if (v >= T) { sx += c.x; sy += c.y; sz += c.z; }
    }
#pragma unroll
    for (int off = 1; off < 32; off <<= 1) {
        sx += __shfl_xor(sx, off);
        sy += __shfl_xor(sy, off);
        sz += __shfl_xor(sz, off);
    }
    if (sl == 0) {
        const float inv = 1.0f / (float)K_NN;
        const int pt = b * N_PTS + n;
        m_out[pt*3+0] = sx * inv;
        m_out[pt*3+1] = sy * inv;
        m_out[pt*3+2] = sz * inv;
    }
}

// ---------------------------------------------------------------------------
// MFMA GEMM cores: A-frags from L2 (swizzled), B from LDS.
// split version: dual accumulators (hi + lo/1024). hi version: single plane.
// ---------------------------------------------------------------------------
template<int MF, int JF>
__device__ __forceinline__ void run_gemm_split(
    const f16* __restrict__ Whi, const f16* __restrict__ Wlo, size_t aoff,
    int NKF, int NK, const f16* Blds, int bstride, int lane,
    floatx4 (&acc)[MF][JF], floatx4 (&accL)[MF][JF])
{
    const int l15 = lane & 15;
    const int lq8 = (lane >> 4) * 8;
    half8 Aa[2*MF], Ab[2*MF];

    auto loada = [&](half8* dst, int kf) {
#pragma unroll
        for (int fm = 0; fm < MF; ++fm) {
            size_t fo = aoff + (size_t)(fm*NKF + kf)*512 + (size_t)lane*8;
            dst[fm*2+0] = *(const half8*)(Whi + fo);
            dst[fm*2+1] = *(const half8*)(Wlo + fo);
        }
    };
    auto step = [&](half8* af, int kf) {
        half8 bq[JF];
#pragma unroll
        for (int fj = 0; fj < JF; ++fj)
            bq[fj] = *(const half8*)&Blds[(fj*16 + l15)*bstride + kf*32 + lq8];
#pragma unroll
        for (int fm = 0; fm < MF; ++fm)
#pragma unroll
            for (int fj = 0; fj < JF; ++fj) {
                acc[fm][fj]  = __builtin_amdgcn_mfma_f32_16x16x32_f16(af[fm*2+0], bq[fj], acc[fm][fj], 0, 0, 0);
                accL[fm][fj] = __builtin_amdgcn_mfma_f32_16x16x32_f16(af[fm*2+1], bq[fj], accL[fm][fj], 0, 0, 0);
            }
    };

    loada(Aa, 0);
#pragma unroll 1
    for (int kf = 0; kf < NK; kf += 2) {
        loada(Ab, kf + 1);
        step(Aa, kf);
        if (kf + 2 < NK) loada(Aa, kf + 2);
        step(Ab, kf + 1);
    }
}

template<int MF, int JF>
__device__ __forceinline__ void run_gemm_hi(
    const f16* __restrict__ Whi, size_t aoff,
    int NKF, int NK, const f16* Blds, int bstride, int lane,
    floatx4 (&acc)[MF][JF])
{
    const int l15 = lane & 15;
    const int lq8 = (lane >> 4) * 8;
    half8 Aa[MF], Ab[MF];

    auto loada = [&](half8* dst, int kf) {
#pragma unroll
        for (int fm = 0; fm < MF; ++fm) {
            size_t fo = aoff + (size_t)(fm*NKF + kf)*512 + (size_t)lane*8;
            dst[fm] = *(const half8*)(Whi + fo);
        }
    };
    auto step = [&](half8* af, int kf) {
        half8 bq[JF];
#pragma unroll
        for (int fj = 0; fj < JF; ++fj)
            bq[fj] = *(const half8*)&Blds[(fj*16 + l15)*bstride + kf*32 + lq8];
#pragma unroll
        for (int fm = 0; fm < MF; ++fm)
#pragma unroll
            for (int fj = 0; fj < JF; ++fj)
                acc[fm][fj] = __builtin_amdgcn_mfma_f32_16x16x32_f16(af[fm], bq[fj], acc[fm][fj], 0, 0, 0);
    };

    loada(Aa, 0);
#pragma unroll 1
    for (int kf = 0; kf < NK; kf += 2) {
        loada(Ab, kf + 1);
        step(Aa, kf);
        if (kf + 2 < NK) loada(Aa, kf + 2);
        step(Ab, kf + 1);
    }
}

__device__ __forceinline__ uint2 pack_res(floatx4 a, floatx4 aL) {
    u16 hh[4];
#pragma unroll
    for (int r = 0; r < 4; ++r) {
        f16 hv = (f16)(a[r] + aL[r] * (1.0f/1024.0f));
        hh[r] = *(u16*)&hv;
    }
    uint2 pv;
    pv.x = (u32)hh[0] | ((u32)hh[1] << 16);
    pv.y = (u32)hh[2] | ((u32)hh[3] << 16);
    return pv;
}

__device__ __forceinline__ uint2 pack_hi(floatx4 a) {
    u16 hh[4];
#pragma unroll
    for (int r = 0; r < 4; ++r) {
        f16 hv = (f16)a[r];
        hh[r] = *(u16*)&hv;
    }
    uint2 pv;
    pv.x = (u32)hh[0] | ((u32)hh[1] << 16);
    pv.y = (u32)hh[2] | ((u32)hh[3] << 16);
    return pv;
}

// ---------------------------------------------------------------------------
// Fused resnet block (as round 8) with D0/D1 run single-plane (relu direction
// errors are damped; dot>=0 points ignore d entirely).
// ---------------------------------------------------------------------------
__global__ __launch_bounds__(256, 2) void resblk_kernel(
    const u16* __restrict__ Wswz,
    int offD0, int offW0, int offD1, int offW1, int offWs,
    const f16* __restrict__ netIn, const float* __restrict__ nm_prev,
    const float* __restrict__ pts, const float* __restrict__ m_buf,
    const float* __restrict__ fcW,
    f16* __restrict__ netOut, float* __restrict__ nm_out, int blk0)
{
    __shared__ struct {
        f16 X[48*264];                              // x (width 256), 25344 B
        union { f16 d[48*264]; float C[48*132]; } Y;// d/y | d1 | float-C scratch
        f16 H[48*136];                              // h / y2 (width 128)
    } s;

    const int tid  = threadIdx.x;
    const int jb   = blockIdx.x * 48;
    const int bB   = blockIdx.x >> 7;               // batch (128 blocks/batch)
    const int lane = tid & 63;
    const int wv   = tid >> 6;                      // 0..3
    const f16* Whi = (const f16*)Wswz;
    const f16* Wlo = Whi + WTOT;

    // ---- stage x into LDS ------------------------------------------------
    if (blk0) {
        float* Hf = (float*)s.H;                    // temp: W(768) p(48)@768 m(48)@816
        const int ptbase = blockIdx.x * 16;
        for (int i = tid; i < 768; i += 256) Hf[i] = fcW[i];
        if (tid < 96) Hf[768 + tid] = (tid < 48) ? pts[ptbase*3 + tid]
                                                 : m_buf[ptbase*3 + tid - 48];
        __syncthreads();
#pragma unroll 1
        for (int it = 0; it < 6; ++it) {
            int idx = tid + 256*it;                 // 0..1535
            int r = idx >> 5;                       // j-row 0..47
            int cg = idx & 31;
            int l = r / 3, v = r - l*3;
            float p0 = Hf[768+l*3], p1 = Hf[768+l*3+1], p2 = Hf[768+l*3+2];
            float m0 = Hf[816+l*3], m1 = Hf[816+l*3+1], m2 = Hf[816+l*3+2];
            float pv[3] = {p0,p1,p2}, mv[3] = {m0,m1,m2};
            int v1 = (v==2) ? 0 : v+1;
            int v2 = (v==0) ? 2 : v-1;
            float av = mv[v] - pv[v];
            float bv = pv[v];
            float cv = mv[v1]*pv[v2] - mv[v2]*pv[v1];
            half8 o;
#pragma unroll
            for (int k = 0; k < 8; ++k) {
                int ch = cg*8 + k;
                o[k] = (f16)(Hf[ch*3+0]*av + Hf[ch*3+1]*bv + Hf[ch*3+2]*cv);
            }
            *(half8*)&s.X[r*264 + cg*8] = o;
        }
    } else {
#pragma unroll 1
        for (int it = 0; it < 6; ++it) {
            int idx = tid + 256*it;
            int r = idx >> 5;
            int cg = idx & 31;
            if (cg < 16) {
                uint4 vv = *(const uint4*)(netIn + (size_t)(jb + r)*128 + cg*8);
                *(uint4*)&s.X[r*264 + cg*8] = vv;
            } else {
                int v = r % 3;                      // jb % 3 == 0
                const float* np = nm_prev + (bB*3+v)*128 + (cg-16)*8;
                half8 o;
#pragma unroll
                for (int k = 0; k < 8; ++k) o[k] = (f16)(np[k] * (1.0f/2048.0f));
                *(half8*)&s.X[r*264 + cg*8] = o;
            }
        }
    }
    __syncthreads();

    // ---- gemm1: d = D0 @ x  (M=256, K=256), hi-only ----------------------
    {
        floatx4 acc[4][3];
#pragma unroll
        for (int a = 0; a < 4; ++a)
#pragma unroll
            for (int b = 0; b < 3; ++b) acc[a][b] = (floatx4){0,0,0,0};
        run_gemm_hi<4,3>(Whi, (size_t)offD0 + (size_t)wv*16384, 8, 8, s.X, 264, lane, acc);
#pragma unroll
        for (int fm = 0; fm < 4; ++fm)
#pragma unroll
            for (int fj = 0; fj < 3; ++fj) {
                int mloc = wv*64 + fm*16 + (lane>>4)*4;
                int jl   = fj*16 + (lane & 15);
                *(uint2*)&s.Y.d[jl*264 + mloc] = pack_hi(acc[fm][fj]);
            }
    }
    __syncthreads();

    // ---- relu1: y = vnrelu(x, d), width 256, in-place in Y ---------------
#pragma unroll 1
    for (int it = 0; it < 2; ++it) {
        int idx = tid + 256*it;                     // 0..511
        int l = idx >> 5, cg = idx & 31;
        half8 xa = *(const half8*)&s.X[(l*3+0)*264 + cg*8];
        half8 xb = *(const half8*)&s.X[(l*3+1)*264 + cg*8];
        half8 xc = *(const half8*)&s.X[(l*3+2)*264 + cg*8];
        half8 da = *(const half8*)&s.Y.d[(l*3+0)*264 + cg*8];
        half8 db = *(const half8*)&s.Y.d[(l*3+1)*264 + cg*8];
        half8 dc = *(const half8*)&s.Y.d[(l*3+2)*264 + cg*8];
        half8 ya, yb, yc;
#pragma unroll
        for (int k = 0; k < 8; ++k) {
            float x0 = (float)xa[k], x1 = (float)xb[k], x2 = (float)xc[k];
            float d0 = (float)da[k], d1 = (float)db[k], d2 = (float)dc[k];
            float dot = x0*d0 + x1*d1 + x2*d2;
            float y0, y1, y2;
            if (dot >= 0.f) { y0 = x0; y1 = x1; y2 = x2; }
            else {
                float dsq = d0*d0 + d1*d1 + d2*d2 + 1e-8f;
                float sc = dot / dsq;
                y0 = x0 - sc*d0; y1 = x1 - sc*d1; y2 = x2 - sc*d2;
            }
            ya[k] = (f16)y0; yb[k] = (f16)y1; yc[k] = (f16)y2;
        }
        *(half8*)&s.Y.d[(l*3+0)*264 + cg*8] = ya;
        *(half8*)&s.Y.d[(l*3+1)*264 + cg*8] = yb;
        *(half8*)&s.Y.d[(l*3+2)*264 + cg*8] = yc;
    }
    __syncthreads();

    // ---- gemm2: h = W0 @ y (M=128, K=256), split -------------------------
    {
        floatx4 acc[2][3], accL[2][3];
#pragma unroll
        for (int a = 0; a < 2; ++a)
#pragma unroll
            for (int b = 0; b < 3; ++b) { acc[a][b] = (floatx4){0,0,0,0}; accL[a][b] = (floatx4){0,0,0,0}; }
        run_gemm_split<2,3>(Whi, Wlo, (size_t)offW0 + (size_t)wv*8192, 8, 8, s.Y.d, 264, lane, acc, accL);
#pragma unroll
        for (int fm = 0; fm < 2; ++fm)
#pragma unroll
            for (int fj = 0; fj < 3; ++fj) {
                int mloc = wv*32 + fm*16 + (lane>>4)*4;
                int jl   = fj*16 + (lane & 15);
                *(uint2*)&s.H[jl*136 + mloc] = pack_res(acc[fm][fj], accL[fm][fj]);
            }
    }
    __syncthreads();

    // ---- gemm3: d1 = D1 @ h (M=128, K=128), hi-only -> Y stride 136 ------
    {
        floatx4 acc[2][3];
#pragma unroll
        for (int a = 0; a < 2; ++a)
#pragma unroll
            for (int b = 0; b < 3; ++b) acc[a][b] = (floatx4){0,0,0,0};
        run_gemm_hi<2,3>(Whi, (size_t)offD1 + (size_t)wv*4096, 4, 4, s.H, 136, lane, acc);
#pragma unroll
        for (int fm = 0; fm < 2; ++fm)
#pragma unroll
            for (int fj = 0; fj < 3; ++fj) {
                int mloc = wv*32 + fm*16 + (lane>>4)*4;
                int jl   = fj*16 + (lane & 15);
                *(uint2*)&s.Y.d[jl*136 + mloc] = pack_hi(acc[fm][fj]);
            }
    }
    __syncthreads();

    // ---- relu2: y2 = vnrelu(h, d1), width 128, write over H --------------
    {
        int l = tid >> 4, cg = tid & 15;
        half8 xa = *(const half8*)&s.H[(l*3+0)*136 + cg*8];
        half8 xb = *(const half8*)&s.H[(l*3+1)*136 + cg*8];
        half8 xc = *(const half8*)&s.H[(l*3+2)*136 + cg*8];
        half8 da = *(const half8*)&s.Y.d[(l*3+0)*136 + cg*8];
        half8 db = *(const half8*)&s.Y.d[(l*3+1)*136 + cg*8];
        half8 dc = *(const half8*)&s.Y.d[(l*3+2)*136 + cg*8];
        half8 ya, yb, yc;
#pragma unroll
        for (int k = 0; k < 8; ++k) {
            float x0 = (float)xa[k], x1 = (float)xb[k], x2 = (float)xc[k];
            float d0 = (float)da[k], d1 = (float)db[k], d2 = (float)dc[k];
            float dot = x0*d0 + x1*d1 + x2*d2;
            float y0, y1, y2;
            if (dot >= 0.f) { y0 = x0; y1 = x1; y2 = x2; }
            else {
                float dsq = d0*d0 + d1*d1 + d2*d2 + 1e-8f;
                float sc = dot / dsq;
                y0 = x0 - sc*d0; y1 = x1 - sc*d1; y2 = x2 - sc*d2;
            }
            ya[k] = (f16)y0; yb[k] = (f16)y1; yc[k] = (f16)y2;
        }
        __syncthreads();
        *(half8*)&s.H[(l*3+0)*136 + cg*8] = ya;
        *(half8*)&s.H[(l*3+1)*136 + cg*8] = yb;
        *(half8*)&s.H[(l*3+2)*136 + cg*8] = yc;
    }
    __syncthreads();

    // ---- gemm4: net = Ws@x + W1@y2 (both split), store + fused pool ------
    {
        floatx4 acc[2][3], accL[2][3];
#pragma unroll
        for (int a = 0; a < 2; ++a)
#pragma unroll
            for (int b = 0; b < 3; ++b) { acc[a][b] = (floatx4){0,0,0,0}; accL[a][b] = (floatx4){0,0,0,0}; }
        run_gemm_split<2,3>(Whi, Wlo, (size_t)offWs + (size_t)wv*8192, 8, 8, s.X, 264, lane, acc, accL);
        run_gemm_split<2,3>(Whi, Wlo, (size_t)offW1 + (size_t)wv*4096, 4, 4, s.H, 136, lane, acc, accL);
#pragma unroll
        for (int fm = 0; fm < 2; ++fm)
#pragma unroll
            for (int fj = 0; fj < 3; ++fj) {
                int mloc = wv*32 + fm*16 + (lane>>4)*4;
                int jl   = fj*16 + (lane & 15);
                floatx4 res;
#pragma unroll
                for (int r = 0; r < 4; ++r) res[r] = acc[fm][fj][r] + accL[fm][fj][r] * (1.0f/1024.0f);
                u16 hh[4];
#pragma unroll
                for (int r = 0; r < 4; ++r) { f16 hv = (f16)res[r]; hh[r] = *(u16*)&hv; }
                uint2 pv;
                pv.x = (u32)hh[0] | ((u32)hh[1] << 16);
                pv.y = (u32)hh[2] | ((u32)hh[3] << 16);
                *(uint2*)(netOut + (size_t)(jb + jl)*128 + mloc) = pv;
                *(floatx4*)&s.Y.C[jl*132 + mloc] = res;
            }
    }
    __syncthreads();

    // ---- pool: sum over 16 points per (v, ch), atomic into nm_out --------
#pragma unroll 1
    for (int idx = tid; idx < 384; idx += 256) {
        int v = idx >> 7, ch = idx & 127;
        float sum = 0.f;
#pragma unroll 1
        for (int pt = 0; pt < 16; ++pt) sum += s.Y.C[(pt*3+v)*132 + ch];
        atomicAdd(nm_out + (bB*3+v)*128 + ch, sum);
    }
}

// ---------------------------------------------------------------------------
// Final head: reads raw pool sums (scale 1/2048). fp32 throughout.
// ---------------------------------------------------------------------------
__global__ __launch_bounds__(128) void final_kernel(const float* __restrict__ nm_sum,
                                                    const float* __restrict__ act_d,
                                                    const float* __restrict__ fc_c,
                                                    float* __restrict__ out)
{
    const int b = blockIdx.x;
    const int c = threadIdx.x;
    __shared__ float xs[128][3];
    __shared__ float ys[128][3];
    xs[c][0] = nm_sum[(b*3+0)*128 + c] * (1.0f/2048.0f);
    xs[c][1] = nm_sum[(b*3+1)*128 + c] * (1.0f/2048.0f);
    xs[c][2] = nm_sum[(b*3+2)*128 + c] * (1.0f/2048.0f);
    __syncthreads();
    float d0 = 0.f, d1 = 0.f, d2 = 0.f;
    for (int i = 0; i < 128; ++i) {
        float w = act_d[c*128 + i];
        d0 = fmaf(w, xs[i][0], d0);
        d1 = fmaf(w, xs[i][1], d1);
        d2 = fmaf(w, xs[i][2], d2);
    }
    float x0 = xs[c][0], x1 = xs[c][1], x2 = xs[c][2];
    float dot = x0*d0 + x1*d1 + x2*d2;
    float y0, y1, y2;
    if (dot >= 0.f) { y0 = x0; y1 = x1; y2 = x2; }
    else {
        float dsq = d0*d0 + d1*d1 + d2*d2 + 1e-8f;
        float sc = dot / dsq;
        y0 = x0 - sc*d0; y1 = x1 - sc*d1; y2 = x2 - sc*d2;
    }
    ys[c][0] = y0; ys[c][1] = y1; ys[c][2] = y2;
    __syncthreads();
    float o0 = 0.f, o1 = 0.f, o2 = 0.f;
    for (int i = 0; i < 128; ++i) {
        float w = fc_c[c*128 + i];
        o0 = fmaf(w, ys[i][0], o0);
        o1 = fmaf(w, ys[i][1], o1);
        o2 = fmaf(w, ys[i][2], o2);
    }
    out[b*384 + c*3 + 0] = o0;
    out[b*384 + c*3 + 1] = o1;
    out[b*384 + c*3 + 2] = o2;
}

// ---------------------------------------------------------------------------
extern "C" void kernel_launch(void* const* d_in, const int* in_sizes, int n_in,
                              void* d_out, int out_size, void* d_ws, size_t ws_size,
                              hipStream_t stream)
{
    const float* p      = (const float*)d_in[0];
    const float* fc_pos = (const float*)d_in[1];
    const float* bd0    = (const float*)d_in[2];
    const float* bW0    = (const float*)d_in[3];
    const float* bd1    = (const float*)d_in[4];
    const float* bW1    = (const float*)d_in[5];
    const float* bWs    = (const float*)d_in[6];
    const float* fc_c   = (const float*)d_in[7];
    const float* act_d  = (const float*)d_in[8];
    float* out = (float*)d_out;

    // Workspace layout (16B-aligned)
    char* w = (char*)d_ws;
    float* m_buf  = (float*)w;  w += 98304;                  // knn means [8192*3]
    float* nm_acc = (float*)w;  w += 5*1536*4;               // pool sums per block
    u16*   Wswz   = (u16*)w;    w += (size_t)2*WTOT*2;       // swizzled split weights
    f16*   netA   = (f16*)w;    w += (size_t)24576*128*2;
    f16*   netB   = (f16*)w;    w += (size_t)24576*128*2;

    prep_kernel<<<dim3(1024 + 3200), dim3(256), 0, stream>>>(
        p, m_buf, bd0, bW0, bd1, bW1, bWs, Wswz, nm_acc);

    f16* nIn = netA;
    f16* nOut = netB;
    for (int blk = 0; blk < 5; ++blk) {
        const int offD0 = blk*65536;
        const int offW0 = 327680 + blk*32768;
        const int offD1 = 491520 + blk*16384;
        const int offW1 = 573440 + blk*16384;
        const int offWs = 655360 + blk*32768;
        const float* nmp = (blk == 0) ? nullptr : (nm_acc + (blk-1)*1536);
        resblk_kernel<<<dim3(512), dim3(256), 0, stream>>>(
            Wswz, offD0, offW0, offD1, offW1, offWs,
            (blk == 0) ? netA : nIn, nmp, p, m_buf, fc_pos,
            nOut, nm_acc + blk*1536, (blk == 0) ? 1 : 0);
        f16* tmp = nIn; nIn = nOut; nOut = tmp;
    }

    final_kernel<<<dim3(4), dim3(128), 0, stream>>>(nm_acc + 4*1536, act_d, fc_c, out);

    (void)in_sizes; (void)n_in; (void)out_size; (void)ws_size;
}